// Round 7
// baseline (2261.848 us; speedup 1.0000x reference)
//
#include <hip/hip_runtime.h>
#include <hip/hip_bf16.h>

// MPNN, fp32 tensors / int32 edge_index. Round-19: r17 base restored for
// pass_a/pass_b (r18's a/b pipelining regressed ~150us: no serialization
// there, TLP already covered latency; VGPR cost cut waves). pass_c keeps
// r17's pipelined no-barrier structure (proven: atomic-drain removal).
// New: LDS diet -> 4 blocks/CU (16 waves, +33% TLP) for pass_b/pass_c:
//  - W2 held in registers (each lane only needs its 2 columns, 16 VGPR);
//    Lw2 (8704B) deleted.
//  - b1v bias table moved to 256B LDS broadcast (frees 32 VGPR, pays for
//    W2 regs).
//  - pass_b's sred overlapped into Lz (wave-private region written after
//    that wave's last Lz read; cross-wave reads after barrier).
// pass_b LDS 40192, pass_c 40704 -> 4 blocks/CU via __launch_bounds__(256,4).
// r14's thrash was at 5 blocks (+67% L2 footprint); 4 (+33%) is the untested
// midpoint - failure signature is FETCH >120MB.

#define BN_EPS 1e-5f
#define NSH 128
#define TPB 4     // 128-edge tiles per block
#define LYS 72    // z-tile row stride (shorts, 144B rows, 16B-aligned)
#define LW1S 168  // W1 LDS col stride (shorts)
#define ASW 66    // node-kernel LDS stride

typedef __attribute__((ext_vector_type(4))) short short4v;
typedef __attribute__((ext_vector_type(8))) short short8;
typedef __attribute__((ext_vector_type(16))) float floatx16;

#define MFMA32 __builtin_amdgcn_mfma_f32_32x32x16_bf16

__device__ __forceinline__ short f2bs(float f) {  // RNE
  union { float f; unsigned u; } x; x.f = f;
  unsigned r = x.u + 0x7fffu + ((x.u >> 16) & 1u);
  return (short)(r >> 16);
}
__device__ __forceinline__ short f2bs_fast(float f) {  // round-half-up
  union { float f; unsigned u; } x; x.f = f;
  return (short)((x.u + 0x8000u) >> 16);
}
__device__ __forceinline__ float bs2f(short s) {
  union { unsigned u; float f; } x;
  x.u = ((unsigned)(unsigned short)s) << 16;
  return x.f;
}

// ---- setup kernels ---------------------------------------------------------

__global__ void lin_in_kernel(const float* __restrict__ x,
                              const float* __restrict__ W,
                              const float* __restrict__ b, float* __restrict__ h,
                              short* __restrict__ hb, int N) {
  int gid = blockIdx.x * blockDim.x + threadIdx.x;
  if (gid >= N * 64) return;
  int n = gid >> 6, o = gid & 63;
  float acc = b[o];
#pragma unroll
  for (int k = 0; k < 6; ++k) acc += x[n * 6 + k] * W[k * 64 + o];
  h[gid] = acc;
  hb[gid] = f2bs(acc);
}

__global__ void deg_kernel(const int* __restrict__ ei, int* __restrict__ deg,
                           int E) {
  int gid = blockIdx.x * blockDim.x + threadIdx.x;
  if (gid < E) atomicAdd(&deg[ei[E + gid]], 1);  // row 1 = dst
}

__global__ void scan_kernel(const int* __restrict__ deg, int* __restrict__ offs,
                            int N) {
  __shared__ int s[1024];
  int t = threadIdx.x;
  int chunk = (N + 1023) >> 10;
  int lo = t * chunk, hi = lo + chunk;
  if (hi > N) hi = N;
  if (lo > N) lo = N;
  int tot = 0;
  for (int i = lo; i < hi; ++i) tot += deg[i];
  s[t] = tot;
  __syncthreads();
  for (int off = 1; off < 1024; off <<= 1) {
    int v = (t >= off) ? s[t - off] : 0;
    __syncthreads();
    s[t] += v;
    __syncthreads();
  }
  int run = s[t] - tot;
  for (int i = lo; i < hi; ++i) {
    offs[i] = run;
    run += deg[i];
  }
}

__global__ void fill_kernel(const int* __restrict__ ei,
                            const int* __restrict__ offs, int* __restrict__ cnt,
                            int* __restrict__ sorted, int E) {
  int gid = blockIdx.x * blockDim.x + threadIdx.x;
  if (gid >= E) return;
  int d = ei[E + gid];
  int pos = offs[d] + atomicAdd(&cnt[d], 1);
  sorted[pos] = gid;
}

__global__ void gather_edges_kernel(const int* __restrict__ ei,
                                    const int* __restrict__ sorted,
                                    const float* __restrict__ ea,
                                    int* __restrict__ dd, int* __restrict__ ds,
                                    short* __restrict__ es, int E, int Epad) {
  int i = blockIdx.x * 256 + threadIdx.x;
  if (i >= Epad) return;
  if (i < E) {
    int e = sorted[i];
    dd[i] = ei[E + e];
    ds[i] = ei[e];
    es[i] = f2bs(ea[e]);
  } else {
    dd[i] = -1;
    ds[i] = 0;
    es[i] = 0;
  }
}

// msg_W1 (L,129,64) -> Wt1 (L,64,160) bf16 n-major, k zero-padded (plain)
__global__ void pack_w1_kernel(const float* __restrict__ W,
                               short* __restrict__ Wt, int L_) {
  int i = blockIdx.x * 256 + threadIdx.x;
  if (i >= L_ * 64 * 160) return;
  int k = i % 160, n = (i / 160) % 64, l = i / (160 * 64);
  Wt[i] = (k < 129) ? f2bs(W[((size_t)l * 129 + k) * 64 + n]) : (short)0;
}

// msg_W2 (L,64,64) -> Wt2 (L,64,64) bf16 n-major (plain)
__global__ void pack_w2_kernel(const float* __restrict__ W,
                               short* __restrict__ Wt, int L_) {
  int i = blockIdx.x * 256 + threadIdx.x;
  if (i >= L_ * 64 * 64) return;
  int k = i % 64, n = (i / 64) % 64, l = i / 4096;
  Wt[i] = f2bs(W[((size_t)l * 64 + k) * 64 + n]);
}

// reduce NSH shards -> BN scale/shift (node side)
__global__ void bn_finalize_kernel(const float* __restrict__ shards,
                                   const float* __restrict__ gamma,
                                   const float* __restrict__ beta, float cnt,
                                   float* __restrict__ ac) {
  int o = threadIdx.x;  // 64 threads
  float s = 0.f, q = 0.f;
  for (int i = 0; i < NSH; ++i) {
    s += shards[i * 128 + o];
    q += shards[i * 128 + 64 + o];
  }
  float mu = s / cnt;
  float var = fmaxf(q / cnt - mu * mu, 0.f);
  float r = rsqrtf(var + BN_EPS);
  float g = gamma[o];
  ac[o] = g * r;
  ac[64 + o] = beta[o] - mu * g * r;
}

// fused: shard reduce -> BN(a,c) -> folded repack (a*W) + folded bias
__global__ void bn_finalize_pack1(const float* __restrict__ shards,
                                  const float* __restrict__ gamma,
                                  const float* __restrict__ beta, float cnt,
                                  const float* __restrict__ W,  // 129x64 layer
                                  const float* __restrict__ b,
                                  short* __restrict__ Wt,
                                  float* __restrict__ bs) {
  __shared__ float sa[64];
  int t = threadIdx.x;
  if (t < 64) {
    float s = 0.f, q = 0.f;
    for (int i = 0; i < NSH; ++i) {
      s += shards[i * 128 + t];
      q += shards[i * 128 + 64 + t];
    }
    float mu = s / cnt;
    float var = fmaxf(q / cnt - mu * mu, 0.f);
    float r = rsqrtf(var + BN_EPS);
    float a = gamma[t] * r;
    float c = beta[t] - mu * a;
    sa[t] = a;
    if (blockIdx.x == 0) bs[t] = a * b[t] + c;
  }
  __syncthreads();
  int i = blockIdx.x * 256 + t;
  if (i < 64 * 160) {
    int k = i % 160, n = i / 160;
    Wt[i] = (k < 129) ? f2bs(W[k * 64 + n] * sa[n]) : (short)0;
  }
}

__global__ void bn_finalize_pack2(const float* __restrict__ shards,
                                  const float* __restrict__ gamma,
                                  const float* __restrict__ beta, float cnt,
                                  const float* __restrict__ W,  // 64x64 layer
                                  const float* __restrict__ b,
                                  short* __restrict__ Wt,
                                  float* __restrict__ bs) {
  __shared__ float sa[64];
  int t = threadIdx.x;
  if (t < 64) {
    float s = 0.f, q = 0.f;
    for (int i = 0; i < NSH; ++i) {
      s += shards[i * 128 + t];
      q += shards[i * 128 + 64 + t];
    }
    float mu = s / cnt;
    float var = fmaxf(q / cnt - mu * mu, 0.f);
    float r = rsqrtf(var + BN_EPS);
    float a = gamma[t] * r;
    float c = beta[t] - mu * a;
    sa[t] = a;
    if (blockIdx.x == 0) bs[t] = a * b[t] + c;
  }
  __syncthreads();
  int i = blockIdx.x * 256 + t;
  if (i < 64 * 64) {
    int k = i % 64, n = i / 64;
    Wt[i] = f2bs(W[k * 64 + n] * sa[n]);
  }
}

// ---- 32x32x16 MFMA edge helpers --------------------------------------------

__device__ __forceinline__ void stage_w1(const short* __restrict__ Wt,
                                         short* Lw, int t) {
#pragma unroll
  for (int i = 0; i < 5; ++i) {
    int c = t + i * 256;
    int col = c / 20, ch = c % 20;
    *(short8*)&Lw[col * LW1S + ch * 8] = *(const short8*)&Wt[col * 160 + ch * 8];
  }
}

// stage the permuted bias table: Lb1[hl][nt][r] (64 floats, broadcast-read)
__device__ __forceinline__ void stage_b1l(const float* __restrict__ b1s,
                                          float* Lb1, int t) {
  if (t < 64) {
    int hl_ = t >> 5, rem = t & 31, nt_ = rem >> 4, r_ = rem & 15;
    Lb1[t] = b1s[nt_ * 32 + (r_ & 3) + 8 * (r_ >> 2) + 4 * hl_];
  }
}

// W2 fragments in registers: each lane needs only its 2 columns.
// w2r[nt][kc] = Wt2[(nt*32+me)*64 + kc*16 + hl*8 .. +7] (same values the
// old Lw2 path delivered to this lane).
__device__ __forceinline__ void load_w2_regs(const short* __restrict__ Wt2,
                                             int me, int hl, short8 w2r[2][4]) {
#pragma unroll
  for (int nt = 0; nt < 2; ++nt) {
    const short* wp = Wt2 + (nt * 32 + me) * 64 + hl * 8;
#pragma unroll
    for (int kc = 0; kc < 4; ++kc) w2r[nt][kc] = *(const short8*)(wp + kc * 16);
  }
}

// gather the 8 feature fragments (dst row + src row) for one edge column
__device__ __forceinline__ void load_frag(const short* __restrict__ hbf, int d,
                                          int sx, int hl, short8 Bf[8]) {
  int dc = d < 0 ? 0 : d;
  const short* hd = hbf + (size_t)dc * 64 + hl * 8;
  const short* hs = hbf + (size_t)sx * 64 + hl * 8;
#pragma unroll
  for (int kc = 0; kc < 4; ++kc) Bf[kc] = *(const short8*)(hd + kc * 16);
#pragma unroll
  for (int kc = 0; kc < 4; ++kc) Bf[4 + kc] = *(const short8*)(hs + kc * 16);
}

// standard GEMM1 (pass_a): A=features (i=edge), B=W1, bias uniform per lane
__device__ __forceinline__ void gemm1_32(const short* __restrict__ hbf,
                                         const short* Lw1,
                                         const float* __restrict__ bias, int d,
                                         int sx, short eav, int me, int hl,
                                         floatx16 acc[2]) {
  const short* hd = hbf + (size_t)d * 64 + hl * 8;
  const short* hs = hbf + (size_t)sx * 64 + hl * 8;
  short8 A[8];
#pragma unroll
  for (int kc = 0; kc < 4; ++kc) A[kc] = *(const short8*)(hd + kc * 16);
#pragma unroll
  for (int kc = 0; kc < 4; ++kc) A[4 + kc] = *(const short8*)(hs + kc * 16);
  short8 a8 = {0, 0, 0, 0, 0, 0, 0, 0};
  if (hl == 0) a8[0] = eav;
#pragma unroll
  for (int nt = 0; nt < 2; ++nt) {
    int col = nt * 32 + me;
    float bv = bias[col];
    floatx16 a;
#pragma unroll
    for (int r = 0; r < 16; ++r) a[r] = bv;
    const short* wp = Lw1 + col * LW1S + hl * 8;
#pragma unroll
    for (int kc = 0; kc < 8; ++kc) {
      short8 B = *(const short8*)(wp + kc * 16);
      a = MFMA32(A[kc], B, a, 0, 0, 0);
    }
    short8 B8 = *(const short8*)(wp + 128);
    a = MFMA32(a8, B8, a, 0, 0, 0);
    acc[nt] = a;
  }
}

// swapped GEMM1 MFMA chain from pre-loaded fragments: A=W1 (i=n1),
// B=features (j=edge) -> D'[n1][edge]
__device__ __forceinline__ void gemm1T_mfma(const short* Lw1,
                                            const short8 Bf[8], short eav,
                                            int me, int hl, floatx16 acc[2]) {
  short8 b8 = {0, 0, 0, 0, 0, 0, 0, 0};
  if (hl == 0) b8[0] = eav;
#pragma unroll
  for (int nt = 0; nt < 2; ++nt) {
    floatx16 a;
#pragma unroll
    for (int r = 0; r < 16; ++r) a[r] = 0.f;
    const short* wp = Lw1 + (nt * 32 + me) * LW1S + hl * 8;
#pragma unroll
    for (int kc = 0; kc < 8; ++kc) {
      short8 A = *(const short8*)(wp + kc * 16);
      a = MFMA32(A, Bf[kc], a, 0, 0, 0);
    }
    short8 A8 = *(const short8*)(wp + 128);
    a = MFMA32(A8, b8, a, 0, 0, 0);
    acc[nt] = a;
  }
}

// swapped GEMM1 (pass b): loads + MFMA in one go
__device__ __forceinline__ void gemm1T_32(const short* __restrict__ hbf,
                                          const short* Lw1, int d, int sx,
                                          short eav, int me, int hl,
                                          floatx16 acc[2]) {
  short8 Bf[8];
  load_frag(hbf, d, sx, hl, Bf);
  gemm1T_mfma(Lw1, Bf, eav, me, hl, acc);
}

// z^T (col=edge, row=n1) + bias(LDS broadcast) + relu -> Lz[edge][n1]
__device__ __forceinline__ void write_z(short* Lz, const floatx16 acc[2],
                                        const float* Lb1, int w, int me,
                                        int hl) {
#pragma unroll
  for (int nt = 0; nt < 2; ++nt)
#pragma unroll
    for (int g4 = 0; g4 < 4; ++g4) {
      float4 bq = *(const float4*)&Lb1[hl * 32 + nt * 16 + 4 * g4];
      int n1b = nt * 32 + 8 * g4 + 4 * hl;
      short4v pk;
      pk[0] = f2bs_fast(fmaxf(acc[nt][4 * g4 + 0] + bq.x, 0.f));
      pk[1] = f2bs_fast(fmaxf(acc[nt][4 * g4 + 1] + bq.y, 0.f));
      pk[2] = f2bs_fast(fmaxf(acc[nt][4 * g4 + 2] + bq.z, 0.f));
      pk[3] = f2bs_fast(fmaxf(acc[nt][4 * g4 + 3] + bq.w, 0.f));
      *(short4v*)&Lz[(w * 32 + me) * LYS + n1b] = pk;
    }
}

// GEMM2 with register-held W2: A=z (i=edge) from Lz, B=w2r
__device__ __forceinline__ void gemm2_w2r(const short* Lz,
                                          const short8 w2r[2][4],
                                          const float bv2[2], int w, int me,
                                          int hl, floatx16 acc[2]) {
  short8 Z[4];
  const short* zp = &Lz[(w * 32 + me) * LYS + hl * 8];
#pragma unroll
  for (int kc = 0; kc < 4; ++kc) Z[kc] = *(const short8*)(zp + kc * 16);
#pragma unroll
  for (int nt = 0; nt < 2; ++nt) {
    floatx16 a;
#pragma unroll
    for (int r = 0; r < 16; ++r) a[r] = bv2[nt];
#pragma unroll
    for (int kc = 0; kc < 4; ++kc) a = MFMA32(Z[kc], w2r[nt][kc], a, 0, 0, 0);
    acc[nt] = a;
  }
}

__device__ __forceinline__ void stats32_acc(const floatx16 acc[2], int idx0,
                                            int w, int hl, int E, bool full,
                                            float sa[2], float qa[2]) {
#pragma unroll
  for (int nt = 0; nt < 2; ++nt) {
    float s = 0.f, q = 0.f;
#pragma unroll
    for (int r = 0; r < 16; ++r) {
      float v = acc[nt][r];
      if (!full) {
        int row = (r & 3) + 8 * (r >> 2) + 4 * hl;
        if (idx0 + w * 32 + row >= E) v = 0.f;
      }
      s += v;
      q += v * v;
    }
    s += __shfl_down(s, 32, 64);
    q += __shfl_down(q, 32, 64);
    sa[nt] += s;
    qa[nt] += q;
  }
}

__device__ __forceinline__ void stats_epilogue(float sred[4][128],
                                               const float sa[2],
                                               const float qa[2], int w,
                                               int lane, int t,
                                               float* __restrict__ stat,
                                               int shard) {
  if (lane < 32) {
#pragma unroll
    for (int nt = 0; nt < 2; ++nt) {
      sred[w][nt * 32 + lane] = sa[nt];
      sred[w][64 + nt * 32 + lane] = qa[nt];
    }
  }
  __syncthreads();
  if (t < 128) {
    float v = sred[0][t] + sred[1][t] + sred[2][t] + sred[3][t];
    atomicAdd(&stat[(size_t)shard * 128 + t], v);
  }
}

// epilogue with shard buffer overlapped into Lz: wave w uses the first 512B
// of its own 4608B Lz row region (written only after its last Lz read).
__device__ __forceinline__ void stats_epilogue_lz(short* Lz, const float sa[2],
                                                  const float qa[2], int w,
                                                  int lane, int t,
                                                  float* __restrict__ stat,
                                                  int shard) {
  float* sw = (float*)&Lz[(w * 32) * LYS];
  if (lane < 32) {
#pragma unroll
    for (int nt = 0; nt < 2; ++nt) {
      sw[nt * 32 + lane] = sa[nt];
      sw[64 + nt * 32 + lane] = qa[nt];
    }
  }
  __syncthreads();
  if (t < 128) {
    float v = 0.f;
#pragma unroll
    for (int wq = 0; wq < 4; ++wq) v += ((float*)&Lz[(wq * 32) * LYS])[t];
    atomicAdd(&stat[(size_t)shard * 128 + t], v);
  }
}

// ---- edge pass kernels -----------------------------------------------------

__global__ __launch_bounds__(256) void edge_pass_a(
    const short* __restrict__ hbf, const short* __restrict__ Wt1,
    const float* __restrict__ b1, const int* __restrict__ dd,
    const int* __restrict__ dsr, const short* __restrict__ es,
    float* __restrict__ stat, int E, int Epad) {
  __shared__ __align__(16) short Lw1[64 * LW1S];
  __shared__ float sred[4][128];
  int t = threadIdx.x;
  stage_w1(Wt1, Lw1, t);
  __syncthreads();
  int w = t >> 6, lane = t & 63, me = lane & 31, hl = lane >> 5;
  float sa[2] = {0.f, 0.f}, qa[2] = {0.f, 0.f};
  for (int it = 0; it < TPB; ++it) {
    int idx0 = (blockIdx.x * TPB + it) * 128;
    if (idx0 >= Epad) break;
    int eg = idx0 + w * 32 + me;
    int d = dd[eg];
    int dc = d < 0 ? 0 : d;
    int sx = dsr[eg];
    short eav = es[eg];
    floatx16 acc[2];
    gemm1_32(hbf, Lw1, b1, dc, sx, eav, me, hl, acc);
    stats32_acc(acc, idx0, w, hl, E, idx0 + 128 <= E, sa, qa);
  }
  stats_epilogue(sred, sa, qa, w, lane, t, stat, blockIdx.x & (NSH - 1));
}

// pass_b (r17 loop structure): W2 in regs, b1 bias via LDS broadcast,
// shard buffer overlapped into Lz -> LDS 40192 -> 4 blocks/CU.
__global__ __launch_bounds__(256, 4) void edge_pass_b(
    const short* __restrict__ hbf, const short* __restrict__ Wt1s,
    const float* __restrict__ b1s, const int* __restrict__ dd,
    const int* __restrict__ dsr, const short* __restrict__ es,
    const short* __restrict__ Wt2, const float* __restrict__ b2,
    float* __restrict__ stat, int E, int Epad) {
  __shared__ __align__(16) short Lw1[64 * LW1S];
  __shared__ __align__(16) short Lz[128 * LYS];
  __shared__ __align__(16) float Lb1[64];
  int t = threadIdx.x;
  int w = t >> 6, lane = t & 63, me = lane & 31, hl = lane >> 5;
  stage_w1(Wt1s, Lw1, t);
  stage_b1l(b1s, Lb1, t);
  short8 w2r[2][4];
  load_w2_regs(Wt2, me, hl, w2r);
  float bv2[2] = {b2[me], b2[32 + me]};
  __syncthreads();
  float sa[2] = {0.f, 0.f}, qa[2] = {0.f, 0.f};
  for (int it = 0; it < TPB; ++it) {
    int idx0 = (blockIdx.x * TPB + it) * 128;
    if (idx0 >= Epad) break;
    int eg = idx0 + w * 32 + me;
    int d = dd[eg];
    int dc = d < 0 ? 0 : d;
    int sx = dsr[eg];
    short eav = es[eg];
    floatx16 acc[2];
    gemm1T_32(hbf, Lw1, dc, sx, eav, me, hl, acc);
    write_z(Lz, acc, Lb1, w, me, hl);  // wave-private rows: no barrier
    floatx16 acc2[2];
    gemm2_w2r(Lz, w2r, bv2, w, me, hl, acc2);  // raw y2 for stats
    stats32_acc(acc2, idx0, w, hl, E, idx0 + 128 <= E, sa, qa);
  }
  stats_epilogue_lz(Lz, sa, qa, w, lane, t, stat, blockIdx.x & (NSH - 1));
}

// pass_c (r17 pipelined, no per-tile barriers): W2 in regs, b1 via LDS
// broadcast -> LDS 40704 -> 4 blocks/CU.
__global__ __launch_bounds__(256, 4) void edge_pass_c(
    const short* __restrict__ hbf, const short* __restrict__ Wt1s,
    const float* __restrict__ b1s, const int* __restrict__ dd,
    const int* __restrict__ dsr, const short* __restrict__ es,
    const short* __restrict__ Wt2s, const float* __restrict__ b2s,
    float* __restrict__ aggr, int E, int Epad) {
  __shared__ __align__(16) short Lw1[64 * LW1S];
  __shared__ __align__(16) short Lz[128 * LYS];
  __shared__ __align__(16) float Lb1[64];
  __shared__ int sdstw[4][32];  // wave-private dst windows
  int t = threadIdx.x;
  int w = t >> 6, lane = t & 63, me = lane & 31, hl = lane >> 5;
  stage_w1(Wt1s, Lw1, t);
  stage_b1l(b1s, Lb1, t);
  short8 w2r[2][4];
  load_w2_regs(Wt2s, me, hl, w2r);
  float bv2[2] = {b2s[me], b2s[32 + me]};
  const int base0 = blockIdx.x * TPB * 128;
  // index pipeline (2 ahead): cur / next
  int d_c, sx_c, d_n, sx_n;
  short eav_c, eav_n;
  {
    int eg = base0 + w * 32 + me;  // tile 0 (always valid: base0 < Epad)
    d_c = dd[eg];
    sx_c = dsr[eg];
    eav_c = es[eg];
    int i1 = base0 + 128;
    if (i1 < Epad) {
      d_n = dd[i1 + w * 32 + me];
      sx_n = dsr[i1 + w * 32 + me];
      eav_n = es[i1 + w * 32 + me];
    } else {
      d_n = -1;
      sx_n = 0;
      eav_n = 0;
    }
  }
  // fragment pipeline (1 ahead): prefetch tile 0
  short8 Bf_c[8], Bf_n[8];
  load_frag(hbf, d_c, sx_c, hl, Bf_c);
  __syncthreads();  // Lw1/Lb1 staged (single barrier in the whole kernel)
#pragma unroll
  for (int it = 0; it < TPB; ++it) {
    int idx0 = base0 + it * 128;
    if (idx0 < Epad) {
      bool nv = (idx0 + 128) < Epad;  // tile it+1 exists (uniform)
      // 1. issue NEXT tile's gathers first (ahead of this tile's atomics)
      if (nv) load_frag(hbf, d_n, sx_n, hl, Bf_n);
      // 2. issue tile it+2's index loads
      int d_2 = -1, sx_2 = 0;
      short eav_2 = 0;
      int i2 = idx0 + 256;
      if (it + 2 < TPB && i2 < Epad) {
        d_2 = dd[i2 + w * 32 + me];
        sx_2 = dsr[i2 + w * 32 + me];
        eav_2 = es[i2 + w * 32 + me];
      }
      // 3. stage own dst window (wave-private; lgkmcnt-ordered, no barrier)
      if (lane < 32) sdstw[w][lane] = d_c;
      // 4. compute current tile
      floatx16 acc[2];
      gemm1T_mfma(Lw1, Bf_c, eav_c, me, hl, acc);
      write_z(Lz, acc, Lb1, w, me, hl);  // wave-private rows
      floatx16 acc2[2];
      gemm2_w2r(Lz, w2r, bv2, w, me, hl, acc2);  // BN2-folded y2
      // 5. register segsum; atomics fire-and-forget
      float s0 = 0.f, s1 = 0.f;
      int d2 = sdstw[w][4 * hl];
#pragma unroll
      for (int g4 = 0; g4 < 4; ++g4) {
#pragma unroll
        for (int j = 0; j < 4; ++j) {
          int r = g4 * 4 + j;
          s0 += fmaxf(acc2[0][r], 0.f);
          s1 += fmaxf(acc2[1][r], 0.f);
          int offn;
          if (j == 3)
            offn = (g4 == 3) ? -1 : 8 * (g4 + 1) + 4 * hl;
          else
            offn = 8 * g4 + 4 * hl + j + 1;
          int dn = (offn < 0) ? -2 : sdstw[w][offn];
          if (d2 != dn) {
            if (d2 >= 0) {
              atomicAdd(&aggr[(size_t)d2 * 64 + me], s0);
              atomicAdd(&aggr[(size_t)d2 * 64 + me + 32], s1);
            }
            s0 = 0.f;
            s1 = 0.f;
          }
          d2 = dn;
        }
      }
      // 6. rotate pipeline state
#pragma unroll
      for (int kc = 0; kc < 8; ++kc) Bf_c[kc] = Bf_n[kc];
      d_c = d_n;
      sx_c = sx_n;
      eav_c = eav_n;
      d_n = d_2;
      sx_n = sx_2;
      eav_n = eav_2;
    }
  }
}

// ---- node pipeline (r5 fp32 tiled, unchanged) ------------------------------

__device__ __forceinline__ void gemm_r2c8(const float* __restrict__ As,
                                          const float* __restrict__ W, int K,
                                          int rg, int cg, float acc[2][8]) {
  const float* ap = As + rg * 2;
  const float* wp = W + cg * 8;
#pragma unroll 4
  for (int k = 0; k < K; ++k) {
    float2 a = *(const float2*)&ap[k * ASW];
    float4 w0 = *(const float4*)&wp[k * 64];
    float4 w1 = *(const float4*)&wp[k * 64 + 4];
    float wv[8] = {w0.x, w0.y, w0.z, w0.w, w1.x, w1.y, w1.z, w1.w};
#pragma unroll
    for (int j = 0; j < 8; ++j) {
      acc[0][j] += a.x * wv[j];
      acc[1][j] += a.y * wv[j];
    }
  }
}

__device__ __forceinline__ void stats_r2c8(const float acc[2][8],
                                           float* __restrict__ shard, int t,
                                           int cg) {
  float s[8], q[8];
#pragma unroll
  for (int j = 0; j < 8; ++j) {
    s[j] = acc[0][j] + acc[1][j];
    q[j] = acc[0][j] * acc[0][j] + acc[1][j] * acc[1][j];
  }
#pragma unroll
  for (int off = 32; off >= 8; off >>= 1) {
#pragma unroll
    for (int j = 0; j < 8; ++j) {
      s[j] += __shfl_down(s[j], off, 64);
      q[j] += __shfl_down(q[j], off, 64);
    }
  }
  if (((t & 63) >> 3) == 0) {
#pragma unroll
    for (int j = 0; j < 8; ++j) {
      atomicAdd(&shard[cg * 8 + j], s[j]);
      atomicAdd(&shard[64 + cg * 8 + j], q[j]);
    }
  }
}

__global__ __launch_bounds__(256) void node_gemm1_v3(
    const float* __restrict__ h, const float* __restrict__ aggr,
    const float* __restrict__ W, const float* __restrict__ b,
    float* __restrict__ u1, float* __restrict__ stat, int N) {
  __shared__ __align__(16) float As[128 * ASW];
  int n0 = blockIdx.x * 64;
  int t = threadIdx.x;
  int c = t & 63, g = t >> 6;
  for (int n = g; n < 64; n += 4) {
    int idx = n0 + n;
    bool v = idx < N;
    As[c * ASW + n] = v ? h[(size_t)idx * 64 + c] : 0.f;
    As[(64 + c) * ASW + n] = v ? aggr[(size_t)idx * 64 + c] : 0.f;
  }
  __syncthreads();
  int rg = t >> 3, cg = t & 7;
  float acc[2][8];
#pragma unroll
  for (int i = 0; i < 2; ++i)
#pragma unroll
    for (int j = 0; j < 8; ++j) acc[i][j] = b[cg * 8 + j];
  gemm_r2c8(As, W, 128, rg, cg, acc);
#pragma unroll
  for (int i = 0; i < 2; ++i) {
    int idx = n0 + rg * 2 + i;
    if (idx < N) {
      *(float4*)&u1[(size_t)idx * 64 + cg * 8] =
          make_float4(acc[i][0], acc[i][1], acc[i][2], acc[i][3]);
      *(float4*)&u1[(size_t)idx * 64 + cg * 8 + 4] =
          make_float4(acc[i][4], acc[i][5], acc[i][6], acc[i][7]);
    } else {
#pragma unroll
      for (int j = 0; j < 8; ++j) acc[i][j] = 0.f;
    }
  }
  stats_r2c8(acc, stat + (size_t)(blockIdx.x & (NSH - 1)) * 128, t, cg);
}

__global__ __launch_bounds__(256) void node_gemm2_v3(
    const float* __restrict__ u1, const float* __restrict__ ac,
    const float* __restrict__ W, const float* __restrict__ b,
    float* __restrict__ u2, float* __restrict__ stat, int N) {
  __shared__ __align__(16) float As[64 * ASW];
  int n0 = blockIdx.x * 64;
  int t = threadIdx.x;
  int c = t & 63, g = t >> 6;
  float a1 = ac[c], c1 = ac[64 + c];
  for (int n = g; n < 64; n += 4) {
    int idx = n0 + n;
    bool v = idx < N;
    As[c * ASW + n] = v ? fmaxf(u1[(size_t)idx * 64 + c] * a1 + c1, 0.f) : 0.f;
  }
  __syncthreads();
  int rg = t >> 3, cg = t & 7;
  float acc[2][8];
#pragma unroll
  for (int i = 0; i < 2; ++i)
#pragma unroll
    for (int j = 0; j < 8; ++j) acc[i][j] = b[cg * 8 + j];
  gemm_r2c8(As, W, 64, rg, cg, acc);
#pragma unroll
  for (int i = 0; i < 2; ++i) {
    int idx = n0 + rg * 2 + i;
    if (idx < N) {
      *(float4*)&u2[(size_t)idx * 64 + cg * 8] =
          make_float4(acc[i][0], acc[i][1], acc[i][2], acc[i][3]);
      *(float4*)&u2[(size_t)idx * 64 + cg * 8 + 4] =
          make_float4(acc[i][4], acc[i][5], acc[i][6], acc[i][7]);
    } else {
#pragma unroll
      for (int j = 0; j < 8; ++j) acc[i][j] = 0.f;
    }
  }
  stats_r2c8(acc, stat + (size_t)(blockIdx.x & (NSH - 1)) * 128, t, cg);
}

__global__ void residual_kernel(float* __restrict__ h, short* __restrict__ hb,
                                const float* __restrict__ u2,
                                const float* __restrict__ ac, int total) {
  int gid = blockIdx.x * blockDim.x + threadIdx.x;
  if (gid >= total) return;
  int o = gid & 63;
  float v = u2[gid] * ac[o] + ac[64 + o];
  float nv = h[gid] + fmaxf(v, 0.f);
  h[gid] = nv;
  hb[gid] = f2bs(nv);
}

__global__ void pred_kernel(const float* __restrict__ h,
                            const float* __restrict__ W,
                            const float* __restrict__ b,
                            float* __restrict__ out, int N) {
  int n = blockIdx.x * blockDim.x + threadIdx.x;
  if (n >= N) return;
  float acc = b[0];
  const float* hr = h + (size_t)n * 64;
#pragma unroll
  for (int o = 0; o < 64; ++o) acc += hr[o] * W[o];
  out[n] = acc;
}

// ---- launch ----------------------------------------------------------------

extern "C" void kernel_launch(void* const* d_in, const int* in_sizes, int n_in,
                              void* d_out, int out_size, void* d_ws,
                              size_t ws_size, hipStream_t stream) {
  const float* x = (const float*)d_in[0];
  const int* ei = (const int*)d_in[1];
  const float* ea = (const float*)d_in[2];
  const float* lin_W = (const float*)d_in[3];
  const float* lin_b = (const float*)d_in[4];
  const float* msg_W1 = (const float*)d_in[5];
  const float* msg_b1 = (const float*)d_in[6];
  const float* msg_g1 = (const float*)d_in[7];
  const float* msg_be1 = (const float*)d_in[8];
  const float* msg_W2 = (const float*)d_in[9];
  const float* msg_b2 = (const float*)d_in[10];
  const float* msg_g2 = (const float*)d_in[11];
  const float* msg_be2 = (const float*)d_in[12];
  const float* upd_W1 = (const float*)d_in[13];
  const float* upd_b1 = (const float*)d_in[14];
  const float* upd_g1 = (const float*)d_in[15];
  const float* upd_be1 = (const float*)d_in[16];
  const float* upd_W2 = (const float*)d_in[17];
  const float* upd_b2 = (const float*)d_in[18];
  const float* upd_g2 = (const float*)d_in[19];
  const float* upd_be2 = (const float*)d_in[20];
  const float* pred_W = (const float*)d_in[21];
  const float* pred_b = (const float*)d_in[22];
  float* out = (float*)d_out;

  const int N = in_sizes[0] / 6;
  const int E = in_sizes[1] / 2;
  const int L = 4;
  const int Epad = ((E + 127) / 128) * 128;

  char* p = (char*)d_ws;
  auto alloc = [&](size_t bytes) {
    void* r = (void*)p;
    p += (bytes + 255) & ~(size_t)255;
    return r;
  };
  float* h = (float*)alloc((size_t)N * 64 * 4);
  short* hb = (short*)alloc((size_t)N * 64 * 2);
  float* aggr = (float*)alloc((size_t)N * 64 * 4);          // contiguous with
  float* stats = (float*)alloc((size_t)4 * NSH * 128 * 4);  // stats: 1 memset
  float* acu1 = (float*)alloc(128 * 4);
  float* acu2 = (float*)alloc(128 * 4);
  float* b1s = (float*)alloc(64 * 4);
  float* b2s = (float*)alloc(64 * 4);
  float* u1 = (float*)alloc((size_t)N * 64 * 4);
  float* u2 = (float*)alloc((size_t)N * 64 * 4);
  int* deg = (int*)alloc((size_t)N * 4);
  int* offs = (int*)alloc((size_t)N * 4);
  int* cnt = (int*)alloc((size_t)N * 4);
  int* sorted = (int*)alloc((size_t)E * 4);
  int* dd = (int*)alloc((size_t)Epad * 4);
  int* dsr = (int*)alloc((size_t)Epad * 4);
  short* es = (short*)alloc((size_t)Epad * 2);
  short* Wt1 = (short*)alloc((size_t)L * 64 * 160 * 2);
  short* Wt2 = (short*)alloc((size_t)L * 64 * 64 * 2);
  short* Wt1s = (short*)alloc((size_t)64 * 160 * 2);
  short* Wt2s = (short*)alloc((size_t)64 * 64 * 2);

  const int B = 256;
  const size_t REG = (size_t)NSH * 128;
  int gridE256 = (E + 255) / 256;
  int NT = Epad / 128;
  int gridEdge = (NT + TPB - 1) / TPB;
  int gridM64 = (N + 63) / 64;
  int gridN64 = (N * 64 + B - 1) / B;
  int gridN = (N + B - 1) / B;

  // setup
  hipMemsetAsync(deg, 0, (size_t)N * 4, stream);
  hipMemsetAsync(cnt, 0, (size_t)N * 4, stream);
  lin_in_kernel<<<gridN64, B, 0, stream>>>(x, lin_W, lin_b, h, hb, N);
  deg_kernel<<<gridE256, B, 0, stream>>>(ei, deg, E);
  scan_kernel<<<1, 1024, 0, stream>>>(deg, offs, N);
  fill_kernel<<<gridE256, B, 0, stream>>>(ei, offs, cnt, sorted, E);
  gather_edges_kernel<<<(Epad + 255) / 256, B, 0, stream>>>(ei, sorted, ea, dd,
                                                            dsr, es, E, Epad);
  pack_w1_kernel<<<(L * 64 * 160 + 255) / 256, B, 0, stream>>>(msg_W1, Wt1, L);
  pack_w2_kernel<<<(L * 64 * 64 + 255) / 256, B, 0, stream>>>(msg_W2, Wt2, L);

  for (int l = 0; l < L; ++l) {
    const short* Wt1l = Wt1 + (size_t)l * 64 * 160;
    const short* Wt2l = Wt2 + (size_t)l * 64 * 64;
    const float* U1 = upd_W1 + (size_t)l * 128 * 64;
    const float* U2 = upd_W2 + (size_t)l * 64 * 64;
    hipMemsetAsync(aggr, 0, (size_t)N * 64 * 4 + (size_t)4 * REG * 4, stream);
    edge_pass_a<<<gridEdge, 256, 0, stream>>>(hb, Wt1l, msg_b1 + l * 64, dd,
                                              dsr, es, stats, E, Epad);
    bn_finalize_pack1<<<(64 * 160 + 255) / 256, B, 0, stream>>>(
        stats, msg_g1 + l * 64, msg_be1 + l * 64, (float)E,
        msg_W1 + (size_t)l * 129 * 64, msg_b1 + l * 64, Wt1s, b1s);
    edge_pass_b<<<gridEdge, 256, 0, stream>>>(hb, Wt1s, b1s, dd, dsr, es, Wt2l,
                                              msg_b2 + l * 64, stats + REG, E,
                                              Epad);
    bn_finalize_pack2<<<(64 * 64 + 255) / 256, B, 0, stream>>>(
        stats + REG, msg_g2 + l * 64, msg_be2 + l * 64, (float)E,
        msg_W2 + (size_t)l * 64 * 64, msg_b2 + l * 64, Wt2s, b2s);
    edge_pass_c<<<gridEdge, 256, 0, stream>>>(hb, Wt1s, b1s, dd, dsr, es, Wt2s,
                                              b2s, aggr, E, Epad);
    node_gemm1_v3<<<gridM64, 256, 0, stream>>>(h, aggr, U1, upd_b1 + l * 64,
                                               u1, stats + 2 * REG, N);
    bn_finalize_kernel<<<1, 64, 0, stream>>>(stats + 2 * REG, upd_g1 + l * 64,
                                             upd_be1 + l * 64, (float)N, acu1);
    node_gemm2_v3<<<gridM64, 256, 0, stream>>>(u1, acu1, U2, upd_b2 + l * 64,
                                               u2, stats + 3 * REG, N);
    bn_finalize_kernel<<<1, 64, 0, stream>>>(stats + 3 * REG, upd_g2 + l * 64,
                                             upd_be2 + l * 64, (float)N, acu2);
    residual_kernel<<<gridN64, B, 0, stream>>>(h, hb, u2, acu2, N * 64);
  }
  pred_kernel<<<gridN, B, 0, stream>>>(h, pred_W, pred_b, out, N);
}

// Round 8
// 1877.700 us; speedup vs baseline: 1.2046x; 1.2046x over previous
//
#include <hip/hip_runtime.h>
#include <hip/hip_bf16.h>

// MPNN, fp32 tensors / int32 edge_index. Round-20: exact r17 restore (best
// verified: 1862us). r19's LDS-diet/4-blocks-CU failed its pre-declared
// signature check (FETCH 57->384MB, WRITE 58->412MB): the aggr atomic RMW
// lines thrash per-XCD L2 at >3 blocks/CU. Occupancy now bracketed both
// sides (3 optimal; 4,5 thrash). Pipelining pass_a/b: regression (r18, no
// serialization to hide). reg-z: regression (r15/r16). This is the proven
// configuration: pass_a/pass_b simple LDS-z, pass_c software-pipelined
// (gathers issued ahead of atomics; wave-private dst staging; zero per-tile
// barriers -> atomics fire-and-forget, no vmcnt(0) drain).

#define BN_EPS 1e-5f
#define NSH 128
#define TPB 4     // 128-edge tiles per block
#define LYS 72    // z-tile row stride (shorts, 144B rows, 16B-aligned)
#define LW1S 168  // W1 LDS col stride (shorts)
#define LW2S 68   // W2 LDS col stride (shorts)
#define ASW 66    // node-kernel LDS stride

typedef __attribute__((ext_vector_type(4))) short short4v;
typedef __attribute__((ext_vector_type(8))) short short8;
typedef __attribute__((ext_vector_type(16))) float floatx16;

#define MFMA32 __builtin_amdgcn_mfma_f32_32x32x16_bf16

__device__ __forceinline__ short f2bs(float f) {  // RNE
  union { float f; unsigned u; } x; x.f = f;
  unsigned r = x.u + 0x7fffu + ((x.u >> 16) & 1u);
  return (short)(r >> 16);
}
__device__ __forceinline__ short f2bs_fast(float f) {  // round-half-up
  union { float f; unsigned u; } x; x.f = f;
  return (short)((x.u + 0x8000u) >> 16);
}
__device__ __forceinline__ float bs2f(short s) {
  union { unsigned u; float f; } x;
  x.u = ((unsigned)(unsigned short)s) << 16;
  return x.f;
}

// ---- setup kernels ---------------------------------------------------------

__global__ void lin_in_kernel(const float* __restrict__ x,
                              const float* __restrict__ W,
                              const float* __restrict__ b, float* __restrict__ h,
                              short* __restrict__ hb, int N) {
  int gid = blockIdx.x * blockDim.x + threadIdx.x;
  if (gid >= N * 64) return;
  int n = gid >> 6, o = gid & 63;
  float acc = b[o];
#pragma unroll
  for (int k = 0; k < 6; ++k) acc += x[n * 6 + k] * W[k * 64 + o];
  h[gid] = acc;
  hb[gid] = f2bs(acc);
}

__global__ void deg_kernel(const int* __restrict__ ei, int* __restrict__ deg,
                           int E) {
  int gid = blockIdx.x * blockDim.x + threadIdx.x;
  if (gid < E) atomicAdd(&deg[ei[E + gid]], 1);  // row 1 = dst
}

__global__ void scan_kernel(const int* __restrict__ deg, int* __restrict__ offs,
                            int N) {
  __shared__ int s[1024];
  int t = threadIdx.x;
  int chunk = (N + 1023) >> 10;
  int lo = t * chunk, hi = lo + chunk;
  if (hi > N) hi = N;
  if (lo > N) lo = N;
  int tot = 0;
  for (int i = lo; i < hi; ++i) tot += deg[i];
  s[t] = tot;
  __syncthreads();
  for (int off = 1; off < 1024; off <<= 1) {
    int v = (t >= off) ? s[t - off] : 0;
    __syncthreads();
    s[t] += v;
    __syncthreads();
  }
  int run = s[t] - tot;
  for (int i = lo; i < hi; ++i) {
    offs[i] = run;
    run += deg[i];
  }
}

__global__ void fill_kernel(const int* __restrict__ ei,
                            const int* __restrict__ offs, int* __restrict__ cnt,
                            int* __restrict__ sorted, int E) {
  int gid = blockIdx.x * blockDim.x + threadIdx.x;
  if (gid >= E) return;
  int d = ei[E + gid];
  int pos = offs[d] + atomicAdd(&cnt[d], 1);
  sorted[pos] = gid;
}

__global__ void gather_edges_kernel(const int* __restrict__ ei,
                                    const int* __restrict__ sorted,
                                    const float* __restrict__ ea,
                                    int* __restrict__ dd, int* __restrict__ ds,
                                    short* __restrict__ es, int E, int Epad) {
  int i = blockIdx.x * 256 + threadIdx.x;
  if (i >= Epad) return;
  if (i < E) {
    int e = sorted[i];
    dd[i] = ei[E + e];
    ds[i] = ei[e];
    es[i] = f2bs(ea[e]);
  } else {
    dd[i] = -1;
    ds[i] = 0;
    es[i] = 0;
  }
}

// msg_W1 (L,129,64) -> Wt1 (L,64,160) bf16 n-major, k zero-padded (plain)
__global__ void pack_w1_kernel(const float* __restrict__ W,
                               short* __restrict__ Wt, int L_) {
  int i = blockIdx.x * 256 + threadIdx.x;
  if (i >= L_ * 64 * 160) return;
  int k = i % 160, n = (i / 160) % 64, l = i / (160 * 64);
  Wt[i] = (k < 129) ? f2bs(W[((size_t)l * 129 + k) * 64 + n]) : (short)0;
}

// msg_W2 (L,64,64) -> Wt2 (L,64,64) bf16 n-major (plain)
__global__ void pack_w2_kernel(const float* __restrict__ W,
                               short* __restrict__ Wt, int L_) {
  int i = blockIdx.x * 256 + threadIdx.x;
  if (i >= L_ * 64 * 64) return;
  int k = i % 64, n = (i / 64) % 64, l = i / 4096;
  Wt[i] = f2bs(W[((size_t)l * 64 + k) * 64 + n]);
}

// reduce NSH shards -> BN scale/shift (node side)
__global__ void bn_finalize_kernel(const float* __restrict__ shards,
                                   const float* __restrict__ gamma,
                                   const float* __restrict__ beta, float cnt,
                                   float* __restrict__ ac) {
  int o = threadIdx.x;  // 64 threads
  float s = 0.f, q = 0.f;
  for (int i = 0; i < NSH; ++i) {
    s += shards[i * 128 + o];
    q += shards[i * 128 + 64 + o];
  }
  float mu = s / cnt;
  float var = fmaxf(q / cnt - mu * mu, 0.f);
  float r = rsqrtf(var + BN_EPS);
  float g = gamma[o];
  ac[o] = g * r;
  ac[64 + o] = beta[o] - mu * g * r;
}

// fused: shard reduce -> BN(a,c) -> folded repack (a*W) + folded bias
__global__ void bn_finalize_pack1(const float* __restrict__ shards,
                                  const float* __restrict__ gamma,
                                  const float* __restrict__ beta, float cnt,
                                  const float* __restrict__ W,  // 129x64 layer
                                  const float* __restrict__ b,
                                  short* __restrict__ Wt,
                                  float* __restrict__ bs) {
  __shared__ float sa[64];
  int t = threadIdx.x;
  if (t < 64) {
    float s = 0.f, q = 0.f;
    for (int i = 0; i < NSH; ++i) {
      s += shards[i * 128 + t];
      q += shards[i * 128 + 64 + t];
    }
    float mu = s / cnt;
    float var = fmaxf(q / cnt - mu * mu, 0.f);
    float r = rsqrtf(var + BN_EPS);
    float a = gamma[t] * r;
    float c = beta[t] - mu * a;
    sa[t] = a;
    if (blockIdx.x == 0) bs[t] = a * b[t] + c;
  }
  __syncthreads();
  int i = blockIdx.x * 256 + t;
  if (i < 64 * 160) {
    int k = i % 160, n = i / 160;
    Wt[i] = (k < 129) ? f2bs(W[k * 64 + n] * sa[n]) : (short)0;
  }
}

__global__ void bn_finalize_pack2(const float* __restrict__ shards,
                                  const float* __restrict__ gamma,
                                  const float* __restrict__ beta, float cnt,
                                  const float* __restrict__ W,  // 64x64 layer
                                  const float* __restrict__ b,
                                  short* __restrict__ Wt,
                                  float* __restrict__ bs) {
  __shared__ float sa[64];
  int t = threadIdx.x;
  if (t < 64) {
    float s = 0.f, q = 0.f;
    for (int i = 0; i < NSH; ++i) {
      s += shards[i * 128 + t];
      q += shards[i * 128 + 64 + t];
    }
    float mu = s / cnt;
    float var = fmaxf(q / cnt - mu * mu, 0.f);
    float r = rsqrtf(var + BN_EPS);
    float a = gamma[t] * r;
    float c = beta[t] - mu * a;
    sa[t] = a;
    if (blockIdx.x == 0) bs[t] = a * b[t] + c;
  }
  __syncthreads();
  int i = blockIdx.x * 256 + t;
  if (i < 64 * 64) {
    int k = i % 64, n = i / 64;
    Wt[i] = f2bs(W[k * 64 + n] * sa[n]);
  }
}

// ---- 32x32x16 MFMA edge helpers --------------------------------------------

__device__ __forceinline__ void stage_w1(const short* __restrict__ Wt,
                                         short* Lw, int t) {
#pragma unroll
  for (int i = 0; i < 5; ++i) {
    int c = t + i * 256;
    int col = c / 20, ch = c % 20;
    *(short8*)&Lw[col * LW1S + ch * 8] = *(const short8*)&Wt[col * 160 + ch * 8];
  }
}
__device__ __forceinline__ void stage_w2(const short* __restrict__ Wt,
                                         short* Lw, int t) {
#pragma unroll
  for (int i = 0; i < 2; ++i) {
    int c = t + i * 256;
    int col = c >> 3, ch = c & 7;
    *(short8*)&Lw[col * LW2S + ch * 8] = *(const short8*)&Wt[col * 64 + ch * 8];
  }
}

// standard GEMM1 (pass_a): A=features (i=edge), B=W1, bias uniform per lane
__device__ __forceinline__ void gemm1_32(const short* __restrict__ hbf,
                                         const short* Lw1,
                                         const float* __restrict__ bias, int d,
                                         int sx, short eav, int me, int hl,
                                         floatx16 acc[2]) {
  const short* hd = hbf + (size_t)d * 64 + hl * 8;
  const short* hs = hbf + (size_t)sx * 64 + hl * 8;
  short8 A[8];
#pragma unroll
  for (int kc = 0; kc < 4; ++kc) A[kc] = *(const short8*)(hd + kc * 16);
#pragma unroll
  for (int kc = 0; kc < 4; ++kc) A[4 + kc] = *(const short8*)(hs + kc * 16);
  short8 a8 = {0, 0, 0, 0, 0, 0, 0, 0};
  if (hl == 0) a8[0] = eav;
#pragma unroll
  for (int nt = 0; nt < 2; ++nt) {
    int col = nt * 32 + me;
    float bv = bias[col];
    floatx16 a;
#pragma unroll
    for (int r = 0; r < 16; ++r) a[r] = bv;
    const short* wp = Lw1 + col * LW1S + hl * 8;
#pragma unroll
    for (int kc = 0; kc < 8; ++kc) {
      short8 B = *(const short8*)(wp + kc * 16);
      a = MFMA32(A[kc], B, a, 0, 0, 0);
    }
    short8 B8 = *(const short8*)(wp + 128);
    a = MFMA32(a8, B8, a, 0, 0, 0);
    acc[nt] = a;
  }
}

// gather the 8 feature fragments (dst row + src row) for one edge column
__device__ __forceinline__ void load_frag(const short* __restrict__ hbf, int d,
                                          int sx, int hl, short8 Bf[8]) {
  int dc = d < 0 ? 0 : d;
  const short* hd = hbf + (size_t)dc * 64 + hl * 8;
  const short* hs = hbf + (size_t)sx * 64 + hl * 8;
#pragma unroll
  for (int kc = 0; kc < 4; ++kc) Bf[kc] = *(const short8*)(hd + kc * 16);
#pragma unroll
  for (int kc = 0; kc < 4; ++kc) Bf[4 + kc] = *(const short8*)(hs + kc * 16);
}

// swapped GEMM1 MFMA chain from pre-loaded fragments: A=W1 (i=n1),
// B=features (j=edge) -> D'[n1][edge]
__device__ __forceinline__ void gemm1T_mfma(const short* Lw1,
                                            const short8 Bf[8], short eav,
                                            int me, int hl, floatx16 acc[2]) {
  short8 b8 = {0, 0, 0, 0, 0, 0, 0, 0};
  if (hl == 0) b8[0] = eav;
#pragma unroll
  for (int nt = 0; nt < 2; ++nt) {
    floatx16 a;
#pragma unroll
    for (int r = 0; r < 16; ++r) a[r] = 0.f;
    const short* wp = Lw1 + (nt * 32 + me) * LW1S + hl * 8;
#pragma unroll
    for (int kc = 0; kc < 8; ++kc) {
      short8 A = *(const short8*)(wp + kc * 16);
      a = MFMA32(A, Bf[kc], a, 0, 0, 0);
    }
    short8 A8 = *(const short8*)(wp + 128);
    a = MFMA32(A8, b8, a, 0, 0, 0);
    acc[nt] = a;
  }
}

// swapped GEMM1 (pass b): loads + MFMA in one go
__device__ __forceinline__ void gemm1T_32(const short* __restrict__ hbf,
                                          const short* Lw1, int d, int sx,
                                          short eav, int me, int hl,
                                          floatx16 acc[2]) {
  short8 Bf[8];
  load_frag(hbf, d, sx, hl, Bf);
  gemm1T_mfma(Lw1, Bf, eav, me, hl, acc);
}

// z^T (col=edge, row=n1) + bias + relu -> Lz[edge][n1]; 8x b64 packed writes
__device__ __forceinline__ void write_z(short* Lz, const floatx16 acc[2],
                                        const float b1v[2][16], int w, int me,
                                        int hl) {
#pragma unroll
  for (int nt = 0; nt < 2; ++nt)
#pragma unroll
    for (int g4 = 0; g4 < 4; ++g4) {
      int n1b = nt * 32 + 8 * g4 + 4 * hl;
      short4v pk;
#pragma unroll
      for (int j = 0; j < 4; ++j) {
        int r = g4 * 4 + j;
        pk[j] = f2bs_fast(fmaxf(acc[nt][r] + b1v[nt][r], 0.f));
      }
      *(short4v*)&Lz[(w * 32 + me) * LYS + n1b] = pk;
    }
}

// standard GEMM2: A=z (i=edge) from Lz, B=W2 (j=n2), bias uniform per lane
__device__ __forceinline__ void gemm2_32(const short* Lz, const short* Lw2,
                                         const float* __restrict__ bias, int w,
                                         int me, int hl, floatx16 acc[2]) {
  short8 Z[4];
  const short* zp = &Lz[(w * 32 + me) * LYS + hl * 8];
#pragma unroll
  for (int kc = 0; kc < 4; ++kc) Z[kc] = *(const short8*)(zp + kc * 16);
#pragma unroll
  for (int nt = 0; nt < 2; ++nt) {
    int col = nt * 32 + me;
    float bv = bias[col];
    floatx16 a;
#pragma unroll
    for (int r = 0; r < 16; ++r) a[r] = bv;
    const short* wp = Lw2 + col * LW2S + hl * 8;
#pragma unroll
    for (int kc = 0; kc < 4; ++kc) {
      short8 B = *(const short8*)(wp + kc * 16);
      a = MFMA32(Z[kc], B, a, 0, 0, 0);
    }
    acc[nt] = a;
  }
}

__device__ __forceinline__ void stats32_acc(const floatx16 acc[2], int idx0,
                                            int w, int hl, int E, bool full,
                                            float sa[2], float qa[2]) {
#pragma unroll
  for (int nt = 0; nt < 2; ++nt) {
    float s = 0.f, q = 0.f;
#pragma unroll
    for (int r = 0; r < 16; ++r) {
      float v = acc[nt][r];
      if (!full) {
        int row = (r & 3) + 8 * (r >> 2) + 4 * hl;
        if (idx0 + w * 32 + row >= E) v = 0.f;
      }
      s += v;
      q += v * v;
    }
    s += __shfl_down(s, 32, 64);
    q += __shfl_down(q, 32, 64);
    sa[nt] += s;
    qa[nt] += q;
  }
}

__device__ __forceinline__ void stats_epilogue(float sred[4][128],
                                               const float sa[2],
                                               const float qa[2], int w,
                                               int lane, int t,
                                               float* __restrict__ stat,
                                               int shard) {
  if (lane < 32) {
#pragma unroll
    for (int nt = 0; nt < 2; ++nt) {
      sred[w][nt * 32 + lane] = sa[nt];
      sred[w][64 + nt * 32 + lane] = qa[nt];
    }
  }
  __syncthreads();
  if (t < 128) {
    float v = sred[0][t] + sred[1][t] + sred[2][t] + sred[3][t];
    atomicAdd(&stat[(size_t)shard * 128 + t], v);
  }
}

// ---- edge pass kernels -----------------------------------------------------

__global__ __launch_bounds__(256) void edge_pass_a(
    const short* __restrict__ hbf, const short* __restrict__ Wt1,
    const float* __restrict__ b1, const int* __restrict__ dd,
    const int* __restrict__ dsr, const short* __restrict__ es,
    float* __restrict__ stat, int E, int Epad) {
  __shared__ __align__(16) short Lw1[64 * LW1S];
  __shared__ float sred[4][128];
  int t = threadIdx.x;
  stage_w1(Wt1, Lw1, t);
  __syncthreads();
  int w = t >> 6, lane = t & 63, me = lane & 31, hl = lane >> 5;
  float sa[2] = {0.f, 0.f}, qa[2] = {0.f, 0.f};
  for (int it = 0; it < TPB; ++it) {
    int idx0 = (blockIdx.x * TPB + it) * 128;
    if (idx0 >= Epad) break;
    int eg = idx0 + w * 32 + me;
    int d = dd[eg];
    int dc = d < 0 ? 0 : d;
    int sx = dsr[eg];
    short eav = es[eg];
    floatx16 acc[2];
    gemm1_32(hbf, Lw1, b1, dc, sx, eav, me, hl, acc);
    stats32_acc(acc, idx0, w, hl, E, idx0 + 128 <= E, sa, qa);
  }
  stats_epilogue(sred, sa, qa, w, lane, t, stat, blockIdx.x & (NSH - 1));
}

__global__ __launch_bounds__(256) void edge_pass_b(
    const short* __restrict__ hbf, const short* __restrict__ Wt1s,
    const float* __restrict__ b1s, const int* __restrict__ dd,
    const int* __restrict__ dsr, const short* __restrict__ es,
    const short* __restrict__ Wt2, const float* __restrict__ b2,
    float* __restrict__ stat, int E, int Epad) {
  __shared__ __align__(16) short Lw1[64 * LW1S];
  __shared__ __align__(16) short Lw2[64 * LW2S];
  __shared__ __align__(16) short Lz[128 * LYS];
  __shared__ float sred[4][128];
  int t = threadIdx.x;
  stage_w1(Wt1s, Lw1, t);
  stage_w2(Wt2, Lw2, t);
  __syncthreads();
  int w = t >> 6, lane = t & 63, me = lane & 31, hl = lane >> 5;
  float b1v[2][16];
#pragma unroll
  for (int nt = 0; nt < 2; ++nt)
#pragma unroll
    for (int r = 0; r < 16; ++r)
      b1v[nt][r] = b1s[nt * 32 + (r & 3) + 8 * (r >> 2) + 4 * hl];
  float sa[2] = {0.f, 0.f}, qa[2] = {0.f, 0.f};
  for (int it = 0; it < TPB; ++it) {
    int idx0 = (blockIdx.x * TPB + it) * 128;
    if (idx0 >= Epad) break;
    int eg = idx0 + w * 32 + me;
    int d = dd[eg];
    int dc = d < 0 ? 0 : d;
    int sx = dsr[eg];
    short eav = es[eg];
    floatx16 acc[2];
    gemm1T_32(hbf, Lw1, dc, sx, eav, me, hl, acc);
    write_z(Lz, acc, b1v, w, me, hl);  // wave-private rows: no barrier
    floatx16 acc2[2];
    gemm2_32(Lz, Lw2, b2, w, me, hl, acc2);  // raw y2 for stats
    stats32_acc(acc2, idx0, w, hl, E, idx0 + 128 <= E, sa, qa);
  }
  stats_epilogue(sred, sa, qa, w, lane, t, stat, blockIdx.x & (NSH - 1));
}

// pipelined pass_c: gathers 1 tile ahead (issued BEFORE current tile's
// atomics -> in-order vmcnt never stalls gathers on atomic retirement),
// indices 2 ahead, wave-private dst staging, zero per-tile barriers.
__global__ __launch_bounds__(256) void edge_pass_c(
    const short* __restrict__ hbf, const short* __restrict__ Wt1s,
    const float* __restrict__ b1s, const int* __restrict__ dd,
    const int* __restrict__ dsr, const short* __restrict__ es,
    const short* __restrict__ Wt2s, const float* __restrict__ b2s,
    float* __restrict__ aggr, int E, int Epad) {
  __shared__ __align__(16) short Lw1[64 * LW1S];
  __shared__ __align__(16) short Lw2[64 * LW2S];
  __shared__ __align__(16) short Lz[128 * LYS];
  __shared__ int sdstw[4][32];  // wave-private dst windows
  int t = threadIdx.x;
  stage_w1(Wt1s, Lw1, t);
  stage_w2(Wt2s, Lw2, t);
  int w = t >> 6, lane = t & 63, me = lane & 31, hl = lane >> 5;
  const int base0 = blockIdx.x * TPB * 128;
  // index pipeline (2 ahead): cur / next
  int d_c, sx_c, d_n, sx_n;
  short eav_c, eav_n;
  {
    int eg = base0 + w * 32 + me;  // tile 0 (always valid: base0 < Epad)
    d_c = dd[eg];
    sx_c = dsr[eg];
    eav_c = es[eg];
    int i1 = base0 + 128;
    if (i1 < Epad) {
      d_n = dd[i1 + w * 32 + me];
      sx_n = dsr[i1 + w * 32 + me];
      eav_n = es[i1 + w * 32 + me];
    } else {
      d_n = -1;
      sx_n = 0;
      eav_n = 0;
    }
  }
  // fragment pipeline (1 ahead): prefetch tile 0
  short8 Bf_c[8], Bf_n[8];
  load_frag(hbf, d_c, sx_c, hl, Bf_c);
  __syncthreads();  // Lw1/Lw2 staged (single barrier in the whole kernel)
  float b1v[2][16];
#pragma unroll
  for (int nt = 0; nt < 2; ++nt)
#pragma unroll
    for (int r = 0; r < 16; ++r)
      b1v[nt][r] = b1s[nt * 32 + (r & 3) + 8 * (r >> 2) + 4 * hl];
#pragma unroll
  for (int it = 0; it < TPB; ++it) {
    int idx0 = base0 + it * 128;
    if (idx0 < Epad) {
      bool nv = (idx0 + 128) < Epad;  // tile it+1 exists (uniform)
      // 1. issue NEXT tile's gathers first (ahead of this tile's atomics)
      if (nv) load_frag(hbf, d_n, sx_n, hl, Bf_n);
      // 2. issue tile it+2's index loads
      int d_2 = -1, sx_2 = 0;
      short eav_2 = 0;
      int i2 = idx0 + 256;
      if (it + 2 < TPB && i2 < Epad) {
        d_2 = dd[i2 + w * 32 + me];
        sx_2 = dsr[i2 + w * 32 + me];
        eav_2 = es[i2 + w * 32 + me];
      }
      // 3. stage own dst window (wave-private; lgkmcnt-ordered, no barrier)
      if (lane < 32) sdstw[w][lane] = d_c;
      // 4. compute current tile
      floatx16 acc[2];
      gemm1T_mfma(Lw1, Bf_c, eav_c, me, hl, acc);
      write_z(Lz, acc, b1v, w, me, hl);  // wave-private rows
      floatx16 acc2[2];
      gemm2_32(Lz, Lw2, b2s, w, me, hl, acc2);  // BN2-folded y2
      // 5. register segsum: lane holds cols (me, me+32) over its 16 sorted
      // edges; half-lane partial flushes OK (atomics commute, runs
      // contiguous); padded edges (dst=-1) never flush. Atomics are
      // fire-and-forget: nothing issued after them is waited on this tile.
      float s0 = 0.f, s1 = 0.f;
      int d2 = sdstw[w][4 * hl];
#pragma unroll
      for (int g4 = 0; g4 < 4; ++g4) {
#pragma unroll
        for (int j = 0; j < 4; ++j) {
          int r = g4 * 4 + j;
          s0 += fmaxf(acc2[0][r], 0.f);
          s1 += fmaxf(acc2[1][r], 0.f);
          int offn;
          if (j == 3)
            offn = (g4 == 3) ? -1 : 8 * (g4 + 1) + 4 * hl;
          else
            offn = 8 * g4 + 4 * hl + j + 1;
          int dn = (offn < 0) ? -2 : sdstw[w][offn];
          if (d2 != dn) {
            if (d2 >= 0) {
              atomicAdd(&aggr[(size_t)d2 * 64 + me], s0);
              atomicAdd(&aggr[(size_t)d2 * 64 + me + 32], s1);
            }
            s0 = 0.f;
            s1 = 0.f;
          }
          d2 = dn;
        }
      }
      // 6. rotate pipeline state
#pragma unroll
      for (int kc = 0; kc < 8; ++kc) Bf_c[kc] = Bf_n[kc];
      d_c = d_n;
      sx_c = sx_n;
      eav_c = eav_n;
      d_n = d_2;
      sx_n = sx_2;
      eav_n = eav_2;
    }
  }
}

// ---- node pipeline (r5 fp32 tiled, unchanged) ------------------------------

__device__ __forceinline__ void gemm_r2c8(const float* __restrict__ As,
                                          const float* __restrict__ W, int K,
                                          int rg, int cg, float acc[2][8]) {
  const float* ap = As + rg * 2;
  const float* wp = W + cg * 8;
#pragma unroll 4
  for (int k = 0; k < K; ++k) {
    float2 a = *(const float2*)&ap[k * ASW];
    float4 w0 = *(const float4*)&wp[k * 64];
    float4 w1 = *(const float4*)&wp[k * 64 + 4];
    float wv[8] = {w0.x, w0.y, w0.z, w0.w, w1.x, w1.y, w1.z, w1.w};
#pragma unroll
    for (int j = 0; j < 8; ++j) {
      acc[0][j] += a.x * wv[j];
      acc[1][j] += a.y * wv[j];
    }
  }
}

__device__ __forceinline__ void stats_r2c8(const float acc[2][8],
                                           float* __restrict__ shard, int t,
                                           int cg) {
  float s[8], q[8];
#pragma unroll
  for (int j = 0; j < 8; ++j) {
    s[j] = acc[0][j] + acc[1][j];
    q[j] = acc[0][j] * acc[0][j] + acc[1][j] * acc[1][j];
  }
#pragma unroll
  for (int off = 32; off >= 8; off >>= 1) {
#pragma unroll
    for (int j = 0; j < 8; ++j) {
      s[j] += __shfl_down(s[j], off, 64);
      q[j] += __shfl_down(q[j], off, 64);
    }
  }
  if (((t & 63) >> 3) == 0) {
#pragma unroll
    for (int j = 0; j < 8; ++j) {
      atomicAdd(&shard[cg * 8 + j], s[j]);
      atomicAdd(&shard[64 + cg * 8 + j], q[j]);
    }
  }
}

__global__ __launch_bounds__(256) void node_gemm1_v3(
    const float* __restrict__ h, const float* __restrict__ aggr,
    const float* __restrict__ W, const float* __restrict__ b,
    float* __restrict__ u1, float* __restrict__ stat, int N) {
  __shared__ __align__(16) float As[128 * ASW];
  int n0 = blockIdx.x * 64;
  int t = threadIdx.x;
  int c = t & 63, g = t >> 6;
  for (int n = g; n < 64; n += 4) {
    int idx = n0 + n;
    bool v = idx < N;
    As[c * ASW + n] = v ? h[(size_t)idx * 64 + c] : 0.f;
    As[(64 + c) * ASW + n] = v ? aggr[(size_t)idx * 64 + c] : 0.f;
  }
  __syncthreads();
  int rg = t >> 3, cg = t & 7;
  float acc[2][8];
#pragma unroll
  for (int i = 0; i < 2; ++i)
#pragma unroll
    for (int j = 0; j < 8; ++j) acc[i][j] = b[cg * 8 + j];
  gemm_r2c8(As, W, 128, rg, cg, acc);
#pragma unroll
  for (int i = 0; i < 2; ++i) {
    int idx = n0 + rg * 2 + i;
    if (idx < N) {
      *(float4*)&u1[(size_t)idx * 64 + cg * 8] =
          make_float4(acc[i][0], acc[i][1], acc[i][2], acc[i][3]);
      *(float4*)&u1[(size_t)idx * 64 + cg * 8 + 4] =
          make_float4(acc[i][4], acc[i][5], acc[i][6], acc[i][7]);
    } else {
#pragma unroll
      for (int j = 0; j < 8; ++j) acc[i][j] = 0.f;
    }
  }
  stats_r2c8(acc, stat + (size_t)(blockIdx.x & (NSH - 1)) * 128, t, cg);
}

__global__ __launch_bounds__(256) void node_gemm2_v3(
    const float* __restrict__ u1, const float* __restrict__ ac,
    const float* __restrict__ W, const float* __restrict__ b,
    float* __restrict__ u2, float* __restrict__ stat, int N) {
  __shared__ __align__(16) float As[64 * ASW];
  int n0 = blockIdx.x * 64;
  int t = threadIdx.x;
  int c = t & 63, g = t >> 6;
  float a1 = ac[c], c1 = ac[64 + c];
  for (int n = g; n < 64; n += 4) {
    int idx = n0 + n;
    bool v = idx < N;
    As[c * ASW + n] = v ? fmaxf(u1[(size_t)idx * 64 + c] * a1 + c1, 0.f) : 0.f;
  }
  __syncthreads();
  int rg = t >> 3, cg = t & 7;
  float acc[2][8];
#pragma unroll
  for (int i = 0; i < 2; ++i)
#pragma unroll
    for (int j = 0; j < 8; ++j) acc[i][j] = b[cg * 8 + j];
  gemm_r2c8(As, W, 64, rg, cg, acc);
#pragma unroll
  for (int i = 0; i < 2; ++i) {
    int idx = n0 + rg * 2 + i;
    if (idx < N) {
      *(float4*)&u2[(size_t)idx * 64 + cg * 8] =
          make_float4(acc[i][0], acc[i][1], acc[i][2], acc[i][3]);
      *(float4*)&u2[(size_t)idx * 64 + cg * 8 + 4] =
          make_float4(acc[i][4], acc[i][5], acc[i][6], acc[i][7]);
    } else {
#pragma unroll
      for (int j = 0; j < 8; ++j) acc[i][j] = 0.f;
    }
  }
  stats_r2c8(acc, stat + (size_t)(blockIdx.x & (NSH - 1)) * 128, t, cg);
}

__global__ void residual_kernel(float* __restrict__ h, short* __restrict__ hb,
                                const float* __restrict__ u2,
                                const float* __restrict__ ac, int total) {
  int gid = blockIdx.x * blockDim.x + threadIdx.x;
  if (gid >= total) return;
  int o = gid & 63;
  float v = u2[gid] * ac[o] + ac[64 + o];
  float nv = h[gid] + fmaxf(v, 0.f);
  h[gid] = nv;
  hb[gid] = f2bs(nv);
}

__global__ void pred_kernel(const float* __restrict__ h,
                            const float* __restrict__ W,
                            const float* __restrict__ b,
                            float* __restrict__ out, int N) {
  int n = blockIdx.x * blockDim.x + threadIdx.x;
  if (n >= N) return;
  float acc = b[0];
  const float* hr = h + (size_t)n * 64;
#pragma unroll
  for (int o = 0; o < 64; ++o) acc += hr[o] * W[o];
  out[n] = acc;
}

// ---- launch ----------------------------------------------------------------

extern "C" void kernel_launch(void* const* d_in, const int* in_sizes, int n_in,
                              void* d_out, int out_size, void* d_ws,
                              size_t ws_size, hipStream_t stream) {
  const float* x = (const float*)d_in[0];
  const int* ei = (const int*)d_in[1];
  const float* ea = (const float*)d_in[2];
  const float* lin_W = (const float*)d_in[3];
  const float* lin_b = (const float*)d_in[4];
  const float* msg_W1 = (const float*)d_in[5];
  const float* msg_b1 = (const float*)d_in[6];
  const float* msg_g1 = (const float*)d_in[7];
  const float* msg_be1 = (const float*)d_in[8];
  const float* msg_W2 = (const float*)d_in[9];
  const float* msg_b2 = (const float*)d_in[10];
  const float* msg_g2 = (const float*)d_in[11];
  const float* msg_be2 = (const float*)d_in[12];
  const float* upd_W1 = (const float*)d_in[13];
  const float* upd_b1 = (const float*)d_in[14];
  const float* upd_g1 = (const float*)d_in[15];
  const float* upd_be1 = (const float*)d_in[16];
  const float* upd_W2 = (const float*)d_in[17];
  const float* upd_b2 = (const float*)d_in[18];
  const float* upd_g2 = (const float*)d_in[19];
  const float* upd_be2 = (const float*)d_in[20];
  const float* pred_W = (const float*)d_in[21];
  const float* pred_b = (const float*)d_in[22];
  float* out = (float*)d_out;

  const int N = in_sizes[0] / 6;
  const int E = in_sizes[1] / 2;
  const int L = 4;
  const int Epad = ((E + 127) / 128) * 128;

  char* p = (char*)d_ws;
  auto alloc = [&](size_t bytes) {
    void* r = (void*)p;
    p += (bytes + 255) & ~(size_t)255;
    return r;
  };
  float* h = (float*)alloc((size_t)N * 64 * 4);
  short* hb = (short*)alloc((size_t)N * 64 * 2);
  float* aggr = (float*)alloc((size_t)N * 64 * 4);          // contiguous with
  float* stats = (float*)alloc((size_t)4 * NSH * 128 * 4);  // stats: 1 memset
  float* acu1 = (float*)alloc(128 * 4);
  float* acu2 = (float*)alloc(128 * 4);
  float* b1s = (float*)alloc(64 * 4);
  float* b2s = (float*)alloc(64 * 4);
  float* u1 = (float*)alloc((size_t)N * 64 * 4);
  float* u2 = (float*)alloc((size_t)N * 64 * 4);
  int* deg = (int*)alloc((size_t)N * 4);
  int* offs = (int*)alloc((size_t)N * 4);
  int* cnt = (int*)alloc((size_t)N * 4);
  int* sorted = (int*)alloc((size_t)E * 4);
  int* dd = (int*)alloc((size_t)Epad * 4);
  int* dsr = (int*)alloc((size_t)Epad * 4);
  short* es = (short*)alloc((size_t)Epad * 2);
  short* Wt1 = (short*)alloc((size_t)L * 64 * 160 * 2);
  short* Wt2 = (short*)alloc((size_t)L * 64 * 64 * 2);
  short* Wt1s = (short*)alloc((size_t)64 * 160 * 2);
  short* Wt2s = (short*)alloc((size_t)64 * 64 * 2);

  const int B = 256;
  const size_t REG = (size_t)NSH * 128;
  int gridE256 = (E + 255) / 256;
  int NT = Epad / 128;
  int gridEdge = (NT + TPB - 1) / TPB;
  int gridM64 = (N + 63) / 64;
  int gridN64 = (N * 64 + B - 1) / B;
  int gridN = (N + B - 1) / B;

  // setup
  hipMemsetAsync(deg, 0, (size_t)N * 4, stream);
  hipMemsetAsync(cnt, 0, (size_t)N * 4, stream);
  lin_in_kernel<<<gridN64, B, 0, stream>>>(x, lin_W, lin_b, h, hb, N);
  deg_kernel<<<gridE256, B, 0, stream>>>(ei, deg, E);
  scan_kernel<<<1, 1024, 0, stream>>>(deg, offs, N);
  fill_kernel<<<gridE256, B, 0, stream>>>(ei, offs, cnt, sorted, E);
  gather_edges_kernel<<<(Epad + 255) / 256, B, 0, stream>>>(ei, sorted, ea, dd,
                                                            dsr, es, E, Epad);
  pack_w1_kernel<<<(L * 64 * 160 + 255) / 256, B, 0, stream>>>(msg_W1, Wt1, L);
  pack_w2_kernel<<<(L * 64 * 64 + 255) / 256, B, 0, stream>>>(msg_W2, Wt2, L);

  for (int l = 0; l < L; ++l) {
    const short* Wt1l = Wt1 + (size_t)l * 64 * 160;
    const short* Wt2l = Wt2 + (size_t)l * 64 * 64;
    const float* U1 = upd_W1 + (size_t)l * 128 * 64;
    const float* U2 = upd_W2 + (size_t)l * 64 * 64;
    hipMemsetAsync(aggr, 0, (size_t)N * 64 * 4 + (size_t)4 * REG * 4, stream);
    edge_pass_a<<<gridEdge, 256, 0, stream>>>(hb, Wt1l, msg_b1 + l * 64, dd,
                                              dsr, es, stats, E, Epad);
    bn_finalize_pack1<<<(64 * 160 + 255) / 256, B, 0, stream>>>(
        stats, msg_g1 + l * 64, msg_be1 + l * 64, (float)E,
        msg_W1 + (size_t)l * 129 * 64, msg_b1 + l * 64, Wt1s, b1s);
    edge_pass_b<<<gridEdge, 256, 0, stream>>>(hb, Wt1s, b1s, dd, dsr, es, Wt2l,
                                              msg_b2 + l * 64, stats + REG, E,
                                              Epad);
    bn_finalize_pack2<<<(64 * 64 + 255) / 256, B, 0, stream>>>(
        stats + REG, msg_g2 + l * 64, msg_be2 + l * 64, (float)E,
        msg_W2 + (size_t)l * 64 * 64, msg_b2 + l * 64, Wt2s, b2s);
    edge_pass_c<<<gridEdge, 256, 0, stream>>>(hb, Wt1s, b1s, dd, dsr, es, Wt2s,
                                              b2s, aggr, E, Epad);
    node_gemm1_v3<<<gridM64, 256, 0, stream>>>(h, aggr, U1, upd_b1 + l * 64,
                                               u1, stats + 2 * REG, N);
    bn_finalize_kernel<<<1, 64, 0, stream>>>(stats + 2 * REG, upd_g1 + l * 64,
                                             upd_be1 + l * 64, (float)N, acu1);
    node_gemm2_v3<<<gridM64, 256, 0, stream>>>(u1, acu1, U2, upd_b2 + l * 64,
                                               u2, stats + 3 * REG, N);
    bn_finalize_kernel<<<1, 64, 0, stream>>>(stats + 3 * REG, upd_g2 + l * 64,
                                             upd_be2 + l * 64, (float)N, acu2);
    residual_kernel<<<gridN64, B, 0, stream>>>(h, hb, u2, acu2, N * 64);
  }
  pred_kernel<<<gridN, B, 0, stream>>>(h, pred_W, pred_b, out, N);
}

// Round 9
// 1813.177 us; speedup vs baseline: 1.2475x; 1.0356x over previous
//
#include <hip/hip_runtime.h>
#include <hip/hip_bf16.h>

// MPNN, fp32 tensors / int32 edge_index. Round-21: r17/r20 proven config
// (1862/1878us) untouched in the edge passes. Off-critical-path cleanup:
//  (1) aggr zeroing folded into node_gemm1 (zero-after-read; each block owns
//      an exclusive 64-node slice; aggr consumed only by node_gemm1). The
//      per-layer 13MB serialized memset shrinks to stats-only 256KB; aggr
//      zeroed once before the layer loop.
//  (2) bn_finalize_kernel parallelized: 256 threads, 4-way shard-split +
//      LDS reduce (was 1x64 threads with a serial 128-iter loop, x8 on the
//      critical path between passes).
// Edge passes: pass_a/b simple (r17), pass_c software-pipelined (gathers
// issued ahead of atomics, wave-private dst staging, zero per-tile
// barriers). Occupancy bracketed: 3 blocks/CU optimal (4,5 thrash L2).

#define BN_EPS 1e-5f
#define NSH 128
#define TPB 4     // 128-edge tiles per block
#define LYS 72    // z-tile row stride (shorts, 144B rows, 16B-aligned)
#define LW1S 168  // W1 LDS col stride (shorts)
#define LW2S 68   // W2 LDS col stride (shorts)
#define ASW 66    // node-kernel LDS stride

typedef __attribute__((ext_vector_type(4))) short short4v;
typedef __attribute__((ext_vector_type(8))) short short8;
typedef __attribute__((ext_vector_type(16))) float floatx16;

#define MFMA32 __builtin_amdgcn_mfma_f32_32x32x16_bf16

__device__ __forceinline__ short f2bs(float f) {  // RNE
  union { float f; unsigned u; } x; x.f = f;
  unsigned r = x.u + 0x7fffu + ((x.u >> 16) & 1u);
  return (short)(r >> 16);
}
__device__ __forceinline__ short f2bs_fast(float f) {  // round-half-up
  union { float f; unsigned u; } x; x.f = f;
  return (short)((x.u + 0x8000u) >> 16);
}
__device__ __forceinline__ float bs2f(short s) {
  union { unsigned u; float f; } x;
  x.u = ((unsigned)(unsigned short)s) << 16;
  return x.f;
}

// ---- setup kernels ---------------------------------------------------------

__global__ void lin_in_kernel(const float* __restrict__ x,
                              const float* __restrict__ W,
                              const float* __restrict__ b, float* __restrict__ h,
                              short* __restrict__ hb, int N) {
  int gid = blockIdx.x * blockDim.x + threadIdx.x;
  if (gid >= N * 64) return;
  int n = gid >> 6, o = gid & 63;
  float acc = b[o];
#pragma unroll
  for (int k = 0; k < 6; ++k) acc += x[n * 6 + k] * W[k * 64 + o];
  h[gid] = acc;
  hb[gid] = f2bs(acc);
}

__global__ void deg_kernel(const int* __restrict__ ei, int* __restrict__ deg,
                           int E) {
  int gid = blockIdx.x * blockDim.x + threadIdx.x;
  if (gid < E) atomicAdd(&deg[ei[E + gid]], 1);  // row 1 = dst
}

__global__ void scan_kernel(const int* __restrict__ deg, int* __restrict__ offs,
                            int N) {
  __shared__ int s[1024];
  int t = threadIdx.x;
  int chunk = (N + 1023) >> 10;
  int lo = t * chunk, hi = lo + chunk;
  if (hi > N) hi = N;
  if (lo > N) lo = N;
  int tot = 0;
  for (int i = lo; i < hi; ++i) tot += deg[i];
  s[t] = tot;
  __syncthreads();
  for (int off = 1; off < 1024; off <<= 1) {
    int v = (t >= off) ? s[t - off] : 0;
    __syncthreads();
    s[t] += v;
    __syncthreads();
  }
  int run = s[t] - tot;
  for (int i = lo; i < hi; ++i) {
    offs[i] = run;
    run += deg[i];
  }
}

__global__ void fill_kernel(const int* __restrict__ ei,
                            const int* __restrict__ offs, int* __restrict__ cnt,
                            int* __restrict__ sorted, int E) {
  int gid = blockIdx.x * blockDim.x + threadIdx.x;
  if (gid >= E) return;
  int d = ei[E + gid];
  int pos = offs[d] + atomicAdd(&cnt[d], 1);
  sorted[pos] = gid;
}

__global__ void gather_edges_kernel(const int* __restrict__ ei,
                                    const int* __restrict__ sorted,
                                    const float* __restrict__ ea,
                                    int* __restrict__ dd, int* __restrict__ ds,
                                    short* __restrict__ es, int E, int Epad) {
  int i = blockIdx.x * 256 + threadIdx.x;
  if (i >= Epad) return;
  if (i < E) {
    int e = sorted[i];
    dd[i] = ei[E + e];
    ds[i] = ei[e];
    es[i] = f2bs(ea[e]);
  } else {
    dd[i] = -1;
    ds[i] = 0;
    es[i] = 0;
  }
}

// msg_W1 (L,129,64) -> Wt1 (L,64,160) bf16 n-major, k zero-padded (plain)
__global__ void pack_w1_kernel(const float* __restrict__ W,
                               short* __restrict__ Wt, int L_) {
  int i = blockIdx.x * 256 + threadIdx.x;
  if (i >= L_ * 64 * 160) return;
  int k = i % 160, n = (i / 160) % 64, l = i / (160 * 64);
  Wt[i] = (k < 129) ? f2bs(W[((size_t)l * 129 + k) * 64 + n]) : (short)0;
}

// msg_W2 (L,64,64) -> Wt2 (L,64,64) bf16 n-major (plain)
__global__ void pack_w2_kernel(const float* __restrict__ W,
                               short* __restrict__ Wt, int L_) {
  int i = blockIdx.x * 256 + threadIdx.x;
  if (i >= L_ * 64 * 64) return;
  int k = i % 64, n = (i / 64) % 64, l = i / 4096;
  Wt[i] = f2bs(W[((size_t)l * 64 + k) * 64 + n]);
}

// reduce NSH shards -> BN scale/shift (node side); 256 threads, 4-way split
__global__ void bn_finalize_kernel(const float* __restrict__ shards,
                                   const float* __restrict__ gamma,
                                   const float* __restrict__ beta, float cnt,
                                   float* __restrict__ ac) {
  __shared__ float red[2][4][64];
  int t = threadIdx.x;
  int o = t & 63, part = t >> 6;  // 4 parts x 32 shards
  float s = 0.f, q = 0.f;
  for (int i = part * 32; i < part * 32 + 32; ++i) {
    s += shards[i * 128 + o];
    q += shards[i * 128 + 64 + o];
  }
  red[0][part][o] = s;
  red[1][part][o] = q;
  __syncthreads();
  if (t < 64) {
    float st = red[0][0][t] + red[0][1][t] + red[0][2][t] + red[0][3][t];
    float qt = red[1][0][t] + red[1][1][t] + red[1][2][t] + red[1][3][t];
    float mu = st / cnt;
    float var = fmaxf(qt / cnt - mu * mu, 0.f);
    float r = rsqrtf(var + BN_EPS);
    float g = gamma[t];
    ac[t] = g * r;
    ac[64 + t] = beta[t] - mu * g * r;
  }
}

// fused: shard reduce -> BN(a,c) -> folded repack (a*W) + folded bias
__global__ void bn_finalize_pack1(const float* __restrict__ shards,
                                  const float* __restrict__ gamma,
                                  const float* __restrict__ beta, float cnt,
                                  const float* __restrict__ W,  // 129x64 layer
                                  const float* __restrict__ b,
                                  short* __restrict__ Wt,
                                  float* __restrict__ bs) {
  __shared__ float sa[64];
  int t = threadIdx.x;
  if (t < 64) {
    float s = 0.f, q = 0.f;
    for (int i = 0; i < NSH; ++i) {
      s += shards[i * 128 + t];
      q += shards[i * 128 + 64 + t];
    }
    float mu = s / cnt;
    float var = fmaxf(q / cnt - mu * mu, 0.f);
    float r = rsqrtf(var + BN_EPS);
    float a = gamma[t] * r;
    float c = beta[t] - mu * a;
    sa[t] = a;
    if (blockIdx.x == 0) bs[t] = a * b[t] + c;
  }
  __syncthreads();
  int i = blockIdx.x * 256 + t;
  if (i < 64 * 160) {
    int k = i % 160, n = i / 160;
    Wt[i] = (k < 129) ? f2bs(W[k * 64 + n] * sa[n]) : (short)0;
  }
}

__global__ void bn_finalize_pack2(const float* __restrict__ shards,
                                  const float* __restrict__ gamma,
                                  const float* __restrict__ beta, float cnt,
                                  const float* __restrict__ W,  // 64x64 layer
                                  const float* __restrict__ b,
                                  short* __restrict__ Wt,
                                  float* __restrict__ bs) {
  __shared__ float sa[64];
  int t = threadIdx.x;
  if (t < 64) {
    float s = 0.f, q = 0.f;
    for (int i = 0; i < NSH; ++i) {
      s += shards[i * 128 + t];
      q += shards[i * 128 + 64 + t];
    }
    float mu = s / cnt;
    float var = fmaxf(q / cnt - mu * mu, 0.f);
    float r = rsqrtf(var + BN_EPS);
    float a = gamma[t] * r;
    float c = beta[t] - mu * a;
    sa[t] = a;
    if (blockIdx.x == 0) bs[t] = a * b[t] + c;
  }
  __syncthreads();
  int i = blockIdx.x * 256 + t;
  if (i < 64 * 64) {
    int k = i % 64, n = i / 64;
    Wt[i] = f2bs(W[k * 64 + n] * sa[n]);
  }
}

// ---- 32x32x16 MFMA edge helpers --------------------------------------------

__device__ __forceinline__ void stage_w1(const short* __restrict__ Wt,
                                         short* Lw, int t) {
#pragma unroll
  for (int i = 0; i < 5; ++i) {
    int c = t + i * 256;
    int col = c / 20, ch = c % 20;
    *(short8*)&Lw[col * LW1S + ch * 8] = *(const short8*)&Wt[col * 160 + ch * 8];
  }
}
__device__ __forceinline__ void stage_w2(const short* __restrict__ Wt,
                                         short* Lw, int t) {
#pragma unroll
  for (int i = 0; i < 2; ++i) {
    int c = t + i * 256;
    int col = c >> 3, ch = c & 7;
    *(short8*)&Lw[col * LW2S + ch * 8] = *(const short8*)&Wt[col * 64 + ch * 8];
  }
}

// standard GEMM1 (pass_a): A=features (i=edge), B=W1, bias uniform per lane
__device__ __forceinline__ void gemm1_32(const short* __restrict__ hbf,
                                         const short* Lw1,
                                         const float* __restrict__ bias, int d,
                                         int sx, short eav, int me, int hl,
                                         floatx16 acc[2]) {
  const short* hd = hbf + (size_t)d * 64 + hl * 8;
  const short* hs = hbf + (size_t)sx * 64 + hl * 8;
  short8 A[8];
#pragma unroll
  for (int kc = 0; kc < 4; ++kc) A[kc] = *(const short8*)(hd + kc * 16);
#pragma unroll
  for (int kc = 0; kc < 4; ++kc) A[4 + kc] = *(const short8*)(hs + kc * 16);
  short8 a8 = {0, 0, 0, 0, 0, 0, 0, 0};
  if (hl == 0) a8[0] = eav;
#pragma unroll
  for (int nt = 0; nt < 2; ++nt) {
    int col = nt * 32 + me;
    float bv = bias[col];
    floatx16 a;
#pragma unroll
    for (int r = 0; r < 16; ++r) a[r] = bv;
    const short* wp = Lw1 + col * LW1S + hl * 8;
#pragma unroll
    for (int kc = 0; kc < 8; ++kc) {
      short8 B = *(const short8*)(wp + kc * 16);
      a = MFMA32(A[kc], B, a, 0, 0, 0);
    }
    short8 B8 = *(const short8*)(wp + 128);
    a = MFMA32(a8, B8, a, 0, 0, 0);
    acc[nt] = a;
  }
}

// gather the 8 feature fragments (dst row + src row) for one edge column
__device__ __forceinline__ void load_frag(const short* __restrict__ hbf, int d,
                                          int sx, int hl, short8 Bf[8]) {
  int dc = d < 0 ? 0 : d;
  const short* hd = hbf + (size_t)dc * 64 + hl * 8;
  const short* hs = hbf + (size_t)sx * 64 + hl * 8;
#pragma unroll
  for (int kc = 0; kc < 4; ++kc) Bf[kc] = *(const short8*)(hd + kc * 16);
#pragma unroll
  for (int kc = 0; kc < 4; ++kc) Bf[4 + kc] = *(const short8*)(hs + kc * 16);
}

// swapped GEMM1 MFMA chain from pre-loaded fragments: A=W1 (i=n1),
// B=features (j=edge) -> D'[n1][edge]
__device__ __forceinline__ void gemm1T_mfma(const short* Lw1,
                                            const short8 Bf[8], short eav,
                                            int me, int hl, floatx16 acc[2]) {
  short8 b8 = {0, 0, 0, 0, 0, 0, 0, 0};
  if (hl == 0) b8[0] = eav;
#pragma unroll
  for (int nt = 0; nt < 2; ++nt) {
    floatx16 a;
#pragma unroll
    for (int r = 0; r < 16; ++r) a[r] = 0.f;
    const short* wp = Lw1 + (nt * 32 + me) * LW1S + hl * 8;
#pragma unroll
    for (int kc = 0; kc < 8; ++kc) {
      short8 A = *(const short8*)(wp + kc * 16);
      a = MFMA32(A, Bf[kc], a, 0, 0, 0);
    }
    short8 A8 = *(const short8*)(wp + 128);
    a = MFMA32(A8, b8, a, 0, 0, 0);
    acc[nt] = a;
  }
}

// swapped GEMM1 (pass b): loads + MFMA in one go
__device__ __forceinline__ void gemm1T_32(const short* __restrict__ hbf,
                                          const short* Lw1, int d, int sx,
                                          short eav, int me, int hl,
                                          floatx16 acc[2]) {
  short8 Bf[8];
  load_frag(hbf, d, sx, hl, Bf);
  gemm1T_mfma(Lw1, Bf, eav, me, hl, acc);
}

// z^T (col=edge, row=n1) + bias + relu -> Lz[edge][n1]; 8x b64 packed writes
__device__ __forceinline__ void write_z(short* Lz, const floatx16 acc[2],
                                        const float b1v[2][16], int w, int me,
                                        int hl) {
#pragma unroll
  for (int nt = 0; nt < 2; ++nt)
#pragma unroll
    for (int g4 = 0; g4 < 4; ++g4) {
      int n1b = nt * 32 + 8 * g4 + 4 * hl;
      short4v pk;
#pragma unroll
      for (int j = 0; j < 4; ++j) {
        int r = g4 * 4 + j;
        pk[j] = f2bs_fast(fmaxf(acc[nt][r] + b1v[nt][r], 0.f));
      }
      *(short4v*)&Lz[(w * 32 + me) * LYS + n1b] = pk;
    }
}

// standard GEMM2: A=z (i=edge) from Lz, B=W2 (j=n2), bias uniform per lane
__device__ __forceinline__ void gemm2_32(const short* Lz, const short* Lw2,
                                         const float* __restrict__ bias, int w,
                                         int me, int hl, floatx16 acc[2]) {
  short8 Z[4];
  const short* zp = &Lz[(w * 32 + me) * LYS + hl * 8];
#pragma unroll
  for (int kc = 0; kc < 4; ++kc) Z[kc] = *(const short8*)(zp + kc * 16);
#pragma unroll
  for (int nt = 0; nt < 2; ++nt) {
    int col = nt * 32 + me;
    float bv = bias[col];
    floatx16 a;
#pragma unroll
    for (int r = 0; r < 16; ++r) a[r] = bv;
    const short* wp = Lw2 + col * LW2S + hl * 8;
#pragma unroll
    for (int kc = 0; kc < 4; ++kc) {
      short8 B = *(const short8*)(wp + kc * 16);
      a = MFMA32(Z[kc], B, a, 0, 0, 0);
    }
    acc[nt] = a;
  }
}

__device__ __forceinline__ void stats32_acc(const floatx16 acc[2], int idx0,
                                            int w, int hl, int E, bool full,
                                            float sa[2], float qa[2]) {
#pragma unroll
  for (int nt = 0; nt < 2; ++nt) {
    float s = 0.f, q = 0.f;
#pragma unroll
    for (int r = 0; r < 16; ++r) {
      float v = acc[nt][r];
      if (!full) {
        int row = (r & 3) + 8 * (r >> 2) + 4 * hl;
        if (idx0 + w * 32 + row >= E) v = 0.f;
      }
      s += v;
      q += v * v;
    }
    s += __shfl_down(s, 32, 64);
    q += __shfl_down(q, 32, 64);
    sa[nt] += s;
    qa[nt] += q;
  }
}

__device__ __forceinline__ void stats_epilogue(float sred[4][128],
                                               const float sa[2],
                                               const float qa[2], int w,
                                               int lane, int t,
                                               float* __restrict__ stat,
                                               int shard) {
  if (lane < 32) {
#pragma unroll
    for (int nt = 0; nt < 2; ++nt) {
      sred[w][nt * 32 + lane] = sa[nt];
      sred[w][64 + nt * 32 + lane] = qa[nt];
    }
  }
  __syncthreads();
  if (t < 128) {
    float v = sred[0][t] + sred[1][t] + sred[2][t] + sred[3][t];
    atomicAdd(&stat[(size_t)shard * 128 + t], v);
  }
}

// ---- edge pass kernels -----------------------------------------------------

__global__ __launch_bounds__(256) void edge_pass_a(
    const short* __restrict__ hbf, const short* __restrict__ Wt1,
    const float* __restrict__ b1, const int* __restrict__ dd,
    const int* __restrict__ dsr, const short* __restrict__ es,
    float* __restrict__ stat, int E, int Epad) {
  __shared__ __align__(16) short Lw1[64 * LW1S];
  __shared__ float sred[4][128];
  int t = threadIdx.x;
  stage_w1(Wt1, Lw1, t);
  __syncthreads();
  int w = t >> 6, lane = t & 63, me = lane & 31, hl = lane >> 5;
  float sa[2] = {0.f, 0.f}, qa[2] = {0.f, 0.f};
  for (int it = 0; it < TPB; ++it) {
    int idx0 = (blockIdx.x * TPB + it) * 128;
    if (idx0 >= Epad) break;
    int eg = idx0 + w * 32 + me;
    int d = dd[eg];
    int dc = d < 0 ? 0 : d;
    int sx = dsr[eg];
    short eav = es[eg];
    floatx16 acc[2];
    gemm1_32(hbf, Lw1, b1, dc, sx, eav, me, hl, acc);
    stats32_acc(acc, idx0, w, hl, E, idx0 + 128 <= E, sa, qa);
  }
  stats_epilogue(sred, sa, qa, w, lane, t, stat, blockIdx.x & (NSH - 1));
}

__global__ __launch_bounds__(256) void edge_pass_b(
    const short* __restrict__ hbf, const short* __restrict__ Wt1s,
    const float* __restrict__ b1s, const int* __restrict__ dd,
    const int* __restrict__ dsr, const short* __restrict__ es,
    const short* __restrict__ Wt2, const float* __restrict__ b2,
    float* __restrict__ stat, int E, int Epad) {
  __shared__ __align__(16) short Lw1[64 * LW1S];
  __shared__ __align__(16) short Lw2[64 * LW2S];
  __shared__ __align__(16) short Lz[128 * LYS];
  __shared__ float sred[4][128];
  int t = threadIdx.x;
  stage_w1(Wt1s, Lw1, t);
  stage_w2(Wt2, Lw2, t);
  __syncthreads();
  int w = t >> 6, lane = t & 63, me = lane & 31, hl = lane >> 5;
  float b1v[2][16];
#pragma unroll
  for (int nt = 0; nt < 2; ++nt)
#pragma unroll
    for (int r = 0; r < 16; ++r)
      b1v[nt][r] = b1s[nt * 32 + (r & 3) + 8 * (r >> 2) + 4 * hl];
  float sa[2] = {0.f, 0.f}, qa[2] = {0.f, 0.f};
  for (int it = 0; it < TPB; ++it) {
    int idx0 = (blockIdx.x * TPB + it) * 128;
    if (idx0 >= Epad) break;
    int eg = idx0 + w * 32 + me;
    int d = dd[eg];
    int dc = d < 0 ? 0 : d;
    int sx = dsr[eg];
    short eav = es[eg];
    floatx16 acc[2];
    gemm1T_32(hbf, Lw1, dc, sx, eav, me, hl, acc);
    write_z(Lz, acc, b1v, w, me, hl);  // wave-private rows: no barrier
    floatx16 acc2[2];
    gemm2_32(Lz, Lw2, b2, w, me, hl, acc2);  // raw y2 for stats
    stats32_acc(acc2, idx0, w, hl, E, idx0 + 128 <= E, sa, qa);
  }
  stats_epilogue(sred, sa, qa, w, lane, t, stat, blockIdx.x & (NSH - 1));
}

// pipelined pass_c: gathers 1 tile ahead (issued BEFORE current tile's
// atomics -> in-order vmcnt never stalls gathers on atomic retirement),
// indices 2 ahead, wave-private dst staging, zero per-tile barriers.
__global__ __launch_bounds__(256) void edge_pass_c(
    const short* __restrict__ hbf, const short* __restrict__ Wt1s,
    const float* __restrict__ b1s, const int* __restrict__ dd,
    const int* __restrict__ dsr, const short* __restrict__ es,
    const short* __restrict__ Wt2s, const float* __restrict__ b2s,
    float* __restrict__ aggr, int E, int Epad) {
  __shared__ __align__(16) short Lw1[64 * LW1S];
  __shared__ __align__(16) short Lw2[64 * LW2S];
  __shared__ __align__(16) short Lz[128 * LYS];
  __shared__ int sdstw[4][32];  // wave-private dst windows
  int t = threadIdx.x;
  stage_w1(Wt1s, Lw1, t);
  stage_w2(Wt2s, Lw2, t);
  int w = t >> 6, lane = t & 63, me = lane & 31, hl = lane >> 5;
  const int base0 = blockIdx.x * TPB * 128;
  // index pipeline (2 ahead): cur / next
  int d_c, sx_c, d_n, sx_n;
  short eav_c, eav_n;
  {
    int eg = base0 + w * 32 + me;  // tile 0 (always valid: base0 < Epad)
    d_c = dd[eg];
    sx_c = dsr[eg];
    eav_c = es[eg];
    int i1 = base0 + 128;
    if (i1 < Epad) {
      d_n = dd[i1 + w * 32 + me];
      sx_n = dsr[i1 + w * 32 + me];
      eav_n = es[i1 + w * 32 + me];
    } else {
      d_n = -1;
      sx_n = 0;
      eav_n = 0;
    }
  }
  // fragment pipeline (1 ahead): prefetch tile 0
  short8 Bf_c[8], Bf_n[8];
  load_frag(hbf, d_c, sx_c, hl, Bf_c);
  __syncthreads();  // Lw1/Lw2 staged (single barrier in the whole kernel)
  float b1v[2][16];
#pragma unroll
  for (int nt = 0; nt < 2; ++nt)
#pragma unroll
    for (int r = 0; r < 16; ++r)
      b1v[nt][r] = b1s[nt * 32 + (r & 3) + 8 * (r >> 2) + 4 * hl];
#pragma unroll
  for (int it = 0; it < TPB; ++it) {
    int idx0 = base0 + it * 128;
    if (idx0 < Epad) {
      bool nv = (idx0 + 128) < Epad;  // tile it+1 exists (uniform)
      // 1. issue NEXT tile's gathers first (ahead of this tile's atomics)
      if (nv) load_frag(hbf, d_n, sx_n, hl, Bf_n);
      // 2. issue tile it+2's index loads
      int d_2 = -1, sx_2 = 0;
      short eav_2 = 0;
      int i2 = idx0 + 256;
      if (it + 2 < TPB && i2 < Epad) {
        d_2 = dd[i2 + w * 32 + me];
        sx_2 = dsr[i2 + w * 32 + me];
        eav_2 = es[i2 + w * 32 + me];
      }
      // 3. stage own dst window (wave-private; lgkmcnt-ordered, no barrier)
      if (lane < 32) sdstw[w][lane] = d_c;
      // 4. compute current tile
      floatx16 acc[2];
      gemm1T_mfma(Lw1, Bf_c, eav_c, me, hl, acc);
      write_z(Lz, acc, b1v, w, me, hl);  // wave-private rows
      floatx16 acc2[2];
      gemm2_32(Lz, Lw2, b2s, w, me, hl, acc2);  // BN2-folded y2
      // 5. register segsum: lane holds cols (me, me+32) over its 16 sorted
      // edges; half-lane partial flushes OK (atomics commute, runs
      // contiguous); padded edges (dst=-1) never flush. Atomics are
      // fire-and-forget: nothing issued after them is waited on this tile.
      float s0 = 0.f, s1 = 0.f;
      int d2 = sdstw[w][4 * hl];
#pragma unroll
      for (int g4 = 0; g4 < 4; ++g4) {
#pragma unroll
        for (int j = 0; j < 4; ++j) {
          int r = g4 * 4 + j;
          s0 += fmaxf(acc2[0][r], 0.f);
          s1 += fmaxf(acc2[1][r], 0.f);
          int offn;
          if (j == 3)
            offn = (g4 == 3) ? -1 : 8 * (g4 + 1) + 4 * hl;
          else
            offn = 8 * g4 + 4 * hl + j + 1;
          int dn = (offn < 0) ? -2 : sdstw[w][offn];
          if (d2 != dn) {
            if (d2 >= 0) {
              atomicAdd(&aggr[(size_t)d2 * 64 + me], s0);
              atomicAdd(&aggr[(size_t)d2 * 64 + me + 32], s1);
            }
            s0 = 0.f;
            s1 = 0.f;
          }
          d2 = dn;
        }
      }
      // 6. rotate pipeline state
#pragma unroll
      for (int kc = 0; kc < 8; ++kc) Bf_c[kc] = Bf_n[kc];
      d_c = d_n;
      sx_c = sx_n;
      eav_c = eav_n;
      d_n = d_2;
      sx_n = sx_2;
      eav_n = eav_2;
    }
  }
}

// ---- node pipeline (r5 fp32 tiled; node_gemm1 now zeroes aggr after read) --

__device__ __forceinline__ void gemm_r2c8(const float* __restrict__ As,
                                          const float* __restrict__ W, int K,
                                          int rg, int cg, float acc[2][8]) {
  const float* ap = As + rg * 2;
  const float* wp = W + cg * 8;
#pragma unroll 4
  for (int k = 0; k < K; ++k) {
    float2 a = *(const float2*)&ap[k * ASW];
    float4 w0 = *(const float4*)&wp[k * 64];
    float4 w1 = *(const float4*)&wp[k * 64 + 4];
    float wv[8] = {w0.x, w0.y, w0.z, w0.w, w1.x, w1.y, w1.z, w1.w};
#pragma unroll
    for (int j = 0; j < 8; ++j) {
      acc[0][j] += a.x * wv[j];
      acc[1][j] += a.y * wv[j];
    }
  }
}

__device__ __forceinline__ void stats_r2c8(const float acc[2][8],
                                           float* __restrict__ shard, int t,
                                           int cg) {
  float s[8], q[8];
#pragma unroll
  for (int j = 0; j < 8; ++j) {
    s[j] = acc[0][j] + acc[1][j];
    q[j] = acc[0][j] * acc[0][j] + acc[1][j] * acc[1][j];
  }
#pragma unroll
  for (int off = 32; off >= 8; off >>= 1) {
#pragma unroll
    for (int j = 0; j < 8; ++j) {
      s[j] += __shfl_down(s[j], off, 64);
      q[j] += __shfl_down(q[j], off, 64);
    }
  }
  if (((t & 63) >> 3) == 0) {
#pragma unroll
    for (int j = 0; j < 8; ++j) {
      atomicAdd(&shard[cg * 8 + j], s[j]);
      atomicAdd(&shard[64 + cg * 8 + j], q[j]);
    }
  }
}

__global__ __launch_bounds__(256) void node_gemm1_v3(
    const float* __restrict__ h, float* __restrict__ aggr,
    const float* __restrict__ W, const float* __restrict__ b,
    float* __restrict__ u1, float* __restrict__ stat, int N) {
  __shared__ __align__(16) float As[128 * ASW];
  int n0 = blockIdx.x * 64;
  int t = threadIdx.x;
  int c = t & 63, g = t >> 6;
  for (int n = g; n < 64; n += 4) {
    int idx = n0 + n;
    bool v = idx < N;
    As[c * ASW + n] = v ? h[(size_t)idx * 64 + c] : 0.f;
    if (v) {
      As[(64 + c) * ASW + n] = aggr[(size_t)idx * 64 + c];
      aggr[(size_t)idx * 64 + c] = 0.f;  // self-clean for next layer's pass_c
    } else {
      As[(64 + c) * ASW + n] = 0.f;
    }
  }
  __syncthreads();
  int rg = t >> 3, cg = t & 7;
  float acc[2][8];
#pragma unroll
  for (int i = 0; i < 2; ++i)
#pragma unroll
    for (int j = 0; j < 8; ++j) acc[i][j] = b[cg * 8 + j];
  gemm_r2c8(As, W, 128, rg, cg, acc);
#pragma unroll
  for (int i = 0; i < 2; ++i) {
    int idx = n0 + rg * 2 + i;
    if (idx < N) {
      *(float4*)&u1[(size_t)idx * 64 + cg * 8] =
          make_float4(acc[i][0], acc[i][1], acc[i][2], acc[i][3]);
      *(float4*)&u1[(size_t)idx * 64 + cg * 8 + 4] =
          make_float4(acc[i][4], acc[i][5], acc[i][6], acc[i][7]);
    } else {
#pragma unroll
      for (int j = 0; j < 8; ++j) acc[i][j] = 0.f;
    }
  }
  stats_r2c8(acc, stat + (size_t)(blockIdx.x & (NSH - 1)) * 128, t, cg);
}

__global__ __launch_bounds__(256) void node_gemm2_v3(
    const float* __restrict__ u1, const float* __restrict__ ac,
    const float* __restrict__ W, const float* __restrict__ b,
    float* __restrict__ u2, float* __restrict__ stat, int N) {
  __shared__ __align__(16) float As[64 * ASW];
  int n0 = blockIdx.x * 64;
  int t = threadIdx.x;
  int c = t & 63, g = t >> 6;
  float a1 = ac[c], c1 = ac[64 + c];
  for (int n = g; n < 64; n += 4) {
    int idx = n0 + n;
    bool v = idx < N;
    As[c * ASW + n] = v ? fmaxf(u1[(size_t)idx * 64 + c] * a1 + c1, 0.f) : 0.f;
  }
  __syncthreads();
  int rg = t >> 3, cg = t & 7;
  float acc[2][8];
#pragma unroll
  for (int i = 0; i < 2; ++i)
#pragma unroll
    for (int j = 0; j < 8; ++j) acc[i][j] = b[cg * 8 + j];
  gemm_r2c8(As, W, 64, rg, cg, acc);
#pragma unroll
  for (int i = 0; i < 2; ++i) {
    int idx = n0 + rg * 2 + i;
    if (idx < N) {
      *(float4*)&u2[(size_t)idx * 64 + cg * 8] =
          make_float4(acc[i][0], acc[i][1], acc[i][2], acc[i][3]);
      *(float4*)&u2[(size_t)idx * 64 + cg * 8 + 4] =
          make_float4(acc[i][4], acc[i][5], acc[i][6], acc[i][7]);
    } else {
#pragma unroll
      for (int j = 0; j < 8; ++j) acc[i][j] = 0.f;
    }
  }
  stats_r2c8(acc, stat + (size_t)(blockIdx.x & (NSH - 1)) * 128, t, cg);
}

__global__ void residual_kernel(float* __restrict__ h, short* __restrict__ hb,
                                const float* __restrict__ u2,
                                const float* __restrict__ ac, int total) {
  int gid = blockIdx.x * blockDim.x + threadIdx.x;
  if (gid >= total) return;
  int o = gid & 63;
  float v = u2[gid] * ac[o] + ac[64 + o];
  float nv = h[gid] + fmaxf(v, 0.f);
  h[gid] = nv;
  hb[gid] = f2bs(nv);
}

__global__ void pred_kernel(const float* __restrict__ h,
                            const float* __restrict__ W,
                            const float* __restrict__ b,
                            float* __restrict__ out, int N) {
  int n = blockIdx.x * blockDim.x + threadIdx.x;
  if (n >= N) return;
  float acc = b[0];
  const float* hr = h + (size_t)n * 64;
#pragma unroll
  for (int o = 0; o < 64; ++o) acc += hr[o] * W[o];
  out[n] = acc;
}

// ---- launch ----------------------------------------------------------------

extern "C" void kernel_launch(void* const* d_in, const int* in_sizes, int n_in,
                              void* d_out, int out_size, void* d_ws,
                              size_t ws_size, hipStream_t stream) {
  const float* x = (const float*)d_in[0];
  const int* ei = (const int*)d_in[1];
  const float* ea = (const float*)d_in[2];
  const float* lin_W = (const float*)d_in[3];
  const float* lin_b = (const float*)d_in[4];
  const float* msg_W1 = (const float*)d_in[5];
  const float* msg_b1 = (const float*)d_in[6];
  const float* msg_g1 = (const float*)d_in[7];
  const float* msg_be1 = (const float*)d_in[8];
  const float* msg_W2 = (const float*)d_in[9];
  const float* msg_b2 = (const float*)d_in[10];
  const float* msg_g2 = (const float*)d_in[11];
  const float* msg_be2 = (const float*)d_in[12];
  const float* upd_W1 = (const float*)d_in[13];
  const float* upd_b1 = (const float*)d_in[14];
  const float* upd_g1 = (const float*)d_in[15];
  const float* upd_be1 = (const float*)d_in[16];
  const float* upd_W2 = (const float*)d_in[17];
  const float* upd_b2 = (const float*)d_in[18];
  const float* upd_g2 = (const float*)d_in[19];
  const float* upd_be2 = (const float*)d_in[20];
  const float* pred_W = (const float*)d_in[21];
  const float* pred_b = (const float*)d_in[22];
  float* out = (float*)d_out;

  const int N = in_sizes[0] / 6;
  const int E = in_sizes[1] / 2;
  const int L = 4;
  const int Epad = ((E + 127) / 128) * 128;

  char* p = (char*)d_ws;
  auto alloc = [&](size_t bytes) {
    void* r = (void*)p;
    p += (bytes + 255) & ~(size_t)255;
    return r;
  };
  float* h = (float*)alloc((size_t)N * 64 * 4);
  short* hb = (short*)alloc((size_t)N * 64 * 2);
  float* aggr = (float*)alloc((size_t)N * 64 * 4);          // contiguous with
  float* stats = (float*)alloc((size_t)4 * NSH * 128 * 4);  // stats
  float* acu1 = (float*)alloc(128 * 4);
  float* acu2 = (float*)alloc(128 * 4);
  float* b1s = (float*)alloc(64 * 4);
  float* b2s = (float*)alloc(64 * 4);
  float* u1 = (float*)alloc((size_t)N * 64 * 4);
  float* u2 = (float*)alloc((size_t)N * 64 * 4);
  int* deg = (int*)alloc((size_t)N * 4);
  int* offs = (int*)alloc((size_t)N * 4);
  int* cnt = (int*)alloc((size_t)N * 4);
  int* sorted = (int*)alloc((size_t)E * 4);
  int* dd = (int*)alloc((size_t)Epad * 4);
  int* dsr = (int*)alloc((size_t)Epad * 4);
  short* es = (short*)alloc((size_t)Epad * 2);
  short* Wt1 = (short*)alloc((size_t)L * 64 * 160 * 2);
  short* Wt2 = (short*)alloc((size_t)L * 64 * 64 * 2);
  short* Wt1s = (short*)alloc((size_t)64 * 160 * 2);
  short* Wt2s = (short*)alloc((size_t)64 * 64 * 2);

  const int B = 256;
  const size_t REG = (size_t)NSH * 128;
  int gridE256 = (E + 255) / 256;
  int NT = Epad / 128;
  int gridEdge = (NT + TPB - 1) / TPB;
  int gridM64 = (N + 63) / 64;
  int gridN64 = (N * 64 + B - 1) / B;
  int gridN = (N + B - 1) / B;

  // setup
  hipMemsetAsync(deg, 0, (size_t)N * 4, stream);
  hipMemsetAsync(cnt, 0, (size_t)N * 4, stream);
  hipMemsetAsync(aggr, 0, (size_t)N * 64 * 4, stream);  // once; then
                                                        // node_gemm1 cleans
  lin_in_kernel<<<gridN64, B, 0, stream>>>(x, lin_W, lin_b, h, hb, N);
  deg_kernel<<<gridE256, B, 0, stream>>>(ei, deg, E);
  scan_kernel<<<1, 1024, 0, stream>>>(deg, offs, N);
  fill_kernel<<<gridE256, B, 0, stream>>>(ei, offs, cnt, sorted, E);
  gather_edges_kernel<<<(Epad + 255) / 256, B, 0, stream>>>(ei, sorted, ea, dd,
                                                            dsr, es, E, Epad);
  pack_w1_kernel<<<(L * 64 * 160 + 255) / 256, B, 0, stream>>>(msg_W1, Wt1, L);
  pack_w2_kernel<<<(L * 64 * 64 + 255) / 256, B, 0, stream>>>(msg_W2, Wt2, L);

  for (int l = 0; l < L; ++l) {
    const short* Wt1l = Wt1 + (size_t)l * 64 * 160;
    const short* Wt2l = Wt2 + (size_t)l * 64 * 64;
    const float* U1 = upd_W1 + (size_t)l * 128 * 64;
    const float* U2 = upd_W2 + (size_t)l * 64 * 64;
    hipMemsetAsync(stats, 0, (size_t)4 * REG * 4, stream);  // stats only
    edge_pass_a<<<gridEdge, 256, 0, stream>>>(hb, Wt1l, msg_b1 + l * 64, dd,
                                              dsr, es, stats, E, Epad);
    bn_finalize_pack1<<<(64 * 160 + 255) / 256, B, 0, stream>>>(
        stats, msg_g1 + l * 64, msg_be1 + l * 64, (float)E,
        msg_W1 + (size_t)l * 129 * 64, msg_b1 + l * 64, Wt1s, b1s);
    edge_pass_b<<<gridEdge, 256, 0, stream>>>(hb, Wt1s, b1s, dd, dsr, es, Wt2l,
                                              msg_b2 + l * 64, stats + REG, E,
                                              Epad);
    bn_finalize_pack2<<<(64 * 64 + 255) / 256, B, 0, stream>>>(
        stats + REG, msg_g2 + l * 64, msg_be2 + l * 64, (float)E,
        msg_W2 + (size_t)l * 64 * 64, msg_b2 + l * 64, Wt2s, b2s);
    edge_pass_c<<<gridEdge, 256, 0, stream>>>(hb, Wt1s, b1s, dd, dsr, es, Wt2s,
                                              b2s, aggr, E, Epad);
    node_gemm1_v3<<<gridM64, 256, 0, stream>>>(h, aggr, U1, upd_b1 + l * 64,
                                               u1, stats + 2 * REG, N);
    bn_finalize_kernel<<<1, 256, 0, stream>>>(stats + 2 * REG, upd_g1 + l * 64,
                                              upd_be1 + l * 64, (float)N,
                                              acu1);
    node_gemm2_v3<<<gridM64, 256, 0, stream>>>(u1, acu1, U2, upd_b2 + l * 64,
                                               u2, stats + 3 * REG, N);
    bn_finalize_kernel<<<1, 256, 0, stream>>>(stats + 3 * REG, upd_g2 + l * 64,
                                              upd_be2 + l * 64, (float)N,
                                              acu2);
    residual_kernel<<<gridN64, B, 0, stream>>>(h, hb, u2, acu2, N * 64);
  }
  pred_kernel<<<gridN, B, 0, stream>>>(h, pred_W, pred_b, out, N);
}

// Round 10
// 1798.579 us; speedup vs baseline: 1.2576x; 1.0081x over previous
//
#include <hip/hip_runtime.h>
#include <hip/hip_bf16.h>

// MPNN, fp32 tensors / int32 edge_index. Round-22: r21 base (1813us, best).
// One change: bn_finalize_pack1/pack2's serial 128-iter shard reduce
// replaced with the same 4-way parallel split used in bn_finalize_kernel
// (r21's proven win): 256 threads, each quarter sums 32 shards, LDS
// tree-reduce, then the weight pack proceeds. These 8 dispatches/run sit
// on the inter-pass critical path (pass_a->pack1->pass_b->pack2->pass_c).
// Edge passes and node pipeline untouched (r17 pass_c pipeline, r21
// zero-after-read aggr, 3 blocks/CU bracketed-optimal).

#define BN_EPS 1e-5f
#define NSH 128
#define TPB 4     // 128-edge tiles per block
#define LYS 72    // z-tile row stride (shorts, 144B rows, 16B-aligned)
#define LW1S 168  // W1 LDS col stride (shorts)
#define LW2S 68   // W2 LDS col stride (shorts)
#define ASW 66    // node-kernel LDS stride

typedef __attribute__((ext_vector_type(4))) short short4v;
typedef __attribute__((ext_vector_type(8))) short short8;
typedef __attribute__((ext_vector_type(16))) float floatx16;

#define MFMA32 __builtin_amdgcn_mfma_f32_32x32x16_bf16

__device__ __forceinline__ short f2bs(float f) {  // RNE
  union { float f; unsigned u; } x; x.f = f;
  unsigned r = x.u + 0x7fffu + ((x.u >> 16) & 1u);
  return (short)(r >> 16);
}
__device__ __forceinline__ short f2bs_fast(float f) {  // round-half-up
  union { float f; unsigned u; } x; x.f = f;
  return (short)((x.u + 0x8000u) >> 16);
}
__device__ __forceinline__ float bs2f(short s) {
  union { unsigned u; float f; } x;
  x.u = ((unsigned)(unsigned short)s) << 16;
  return x.f;
}

// ---- setup kernels ---------------------------------------------------------

__global__ void lin_in_kernel(const float* __restrict__ x,
                              const float* __restrict__ W,
                              const float* __restrict__ b, float* __restrict__ h,
                              short* __restrict__ hb, int N) {
  int gid = blockIdx.x * blockDim.x + threadIdx.x;
  if (gid >= N * 64) return;
  int n = gid >> 6, o = gid & 63;
  float acc = b[o];
#pragma unroll
  for (int k = 0; k < 6; ++k) acc += x[n * 6 + k] * W[k * 64 + o];
  h[gid] = acc;
  hb[gid] = f2bs(acc);
}

__global__ void deg_kernel(const int* __restrict__ ei, int* __restrict__ deg,
                           int E) {
  int gid = blockIdx.x * blockDim.x + threadIdx.x;
  if (gid < E) atomicAdd(&deg[ei[E + gid]], 1);  // row 1 = dst
}

__global__ void scan_kernel(const int* __restrict__ deg, int* __restrict__ offs,
                            int N) {
  __shared__ int s[1024];
  int t = threadIdx.x;
  int chunk = (N + 1023) >> 10;
  int lo = t * chunk, hi = lo + chunk;
  if (hi > N) hi = N;
  if (lo > N) lo = N;
  int tot = 0;
  for (int i = lo; i < hi; ++i) tot += deg[i];
  s[t] = tot;
  __syncthreads();
  for (int off = 1; off < 1024; off <<= 1) {
    int v = (t >= off) ? s[t - off] : 0;
    __syncthreads();
    s[t] += v;
    __syncthreads();
  }
  int run = s[t] - tot;
  for (int i = lo; i < hi; ++i) {
    offs[i] = run;
    run += deg[i];
  }
}

__global__ void fill_kernel(const int* __restrict__ ei,
                            const int* __restrict__ offs, int* __restrict__ cnt,
                            int* __restrict__ sorted, int E) {
  int gid = blockIdx.x * blockDim.x + threadIdx.x;
  if (gid >= E) return;
  int d = ei[E + gid];
  int pos = offs[d] + atomicAdd(&cnt[d], 1);
  sorted[pos] = gid;
}

__global__ void gather_edges_kernel(const int* __restrict__ ei,
                                    const int* __restrict__ sorted,
                                    const float* __restrict__ ea,
                                    int* __restrict__ dd, int* __restrict__ ds,
                                    short* __restrict__ es, int E, int Epad) {
  int i = blockIdx.x * 256 + threadIdx.x;
  if (i >= Epad) return;
  if (i < E) {
    int e = sorted[i];
    dd[i] = ei[E + e];
    ds[i] = ei[e];
    es[i] = f2bs(ea[e]);
  } else {
    dd[i] = -1;
    ds[i] = 0;
    es[i] = 0;
  }
}

// msg_W1 (L,129,64) -> Wt1 (L,64,160) bf16 n-major, k zero-padded (plain)
__global__ void pack_w1_kernel(const float* __restrict__ W,
                               short* __restrict__ Wt, int L_) {
  int i = blockIdx.x * 256 + threadIdx.x;
  if (i >= L_ * 64 * 160) return;
  int k = i % 160, n = (i / 160) % 64, l = i / (160 * 64);
  Wt[i] = (k < 129) ? f2bs(W[((size_t)l * 129 + k) * 64 + n]) : (short)0;
}

// msg_W2 (L,64,64) -> Wt2 (L,64,64) bf16 n-major (plain)
__global__ void pack_w2_kernel(const float* __restrict__ W,
                               short* __restrict__ Wt, int L_) {
  int i = blockIdx.x * 256 + threadIdx.x;
  if (i >= L_ * 64 * 64) return;
  int k = i % 64, n = (i / 64) % 64, l = i / 4096;
  Wt[i] = f2bs(W[((size_t)l * 64 + k) * 64 + n]);
}

// reduce NSH shards -> BN scale/shift (node side); 256 threads, 4-way split
__global__ void bn_finalize_kernel(const float* __restrict__ shards,
                                   const float* __restrict__ gamma,
                                   const float* __restrict__ beta, float cnt,
                                   float* __restrict__ ac) {
  __shared__ float red[2][4][64];
  int t = threadIdx.x;
  int o = t & 63, part = t >> 6;  // 4 parts x 32 shards
  float s = 0.f, q = 0.f;
  for (int i = part * 32; i < part * 32 + 32; ++i) {
    s += shards[i * 128 + o];
    q += shards[i * 128 + 64 + o];
  }
  red[0][part][o] = s;
  red[1][part][o] = q;
  __syncthreads();
  if (t < 64) {
    float st = red[0][0][t] + red[0][1][t] + red[0][2][t] + red[0][3][t];
    float qt = red[1][0][t] + red[1][1][t] + red[1][2][t] + red[1][3][t];
    float mu = st / cnt;
    float var = fmaxf(qt / cnt - mu * mu, 0.f);
    float r = rsqrtf(var + BN_EPS);
    float g = gamma[t];
    ac[t] = g * r;
    ac[64 + t] = beta[t] - mu * g * r;
  }
}

// fused: 4-way parallel shard reduce -> BN(a,c) -> folded repack (a*W) + bias
__global__ void bn_finalize_pack1(const float* __restrict__ shards,
                                  const float* __restrict__ gamma,
                                  const float* __restrict__ beta, float cnt,
                                  const float* __restrict__ W,  // 129x64 layer
                                  const float* __restrict__ b,
                                  short* __restrict__ Wt,
                                  float* __restrict__ bs) {
  __shared__ float red[2][4][64];
  __shared__ float sa[64];
  int t = threadIdx.x;
  int o = t & 63, part = t >> 6;  // 4 parts x 32 shards
  {
    float s = 0.f, q = 0.f;
    for (int i = part * 32; i < part * 32 + 32; ++i) {
      s += shards[i * 128 + o];
      q += shards[i * 128 + 64 + o];
    }
    red[0][part][o] = s;
    red[1][part][o] = q;
  }
  __syncthreads();
  if (t < 64) {
    float st = red[0][0][t] + red[0][1][t] + red[0][2][t] + red[0][3][t];
    float qt = red[1][0][t] + red[1][1][t] + red[1][2][t] + red[1][3][t];
    float mu = st / cnt;
    float var = fmaxf(qt / cnt - mu * mu, 0.f);
    float r = rsqrtf(var + BN_EPS);
    float a = gamma[t] * r;
    float c = beta[t] - mu * a;
    sa[t] = a;
    if (blockIdx.x == 0) bs[t] = a * b[t] + c;
  }
  __syncthreads();
  int i = blockIdx.x * 256 + t;
  if (i < 64 * 160) {
    int k = i % 160, n = i / 160;
    Wt[i] = (k < 129) ? f2bs(W[k * 64 + n] * sa[n]) : (short)0;
  }
}

__global__ void bn_finalize_pack2(const float* __restrict__ shards,
                                  const float* __restrict__ gamma,
                                  const float* __restrict__ beta, float cnt,
                                  const float* __restrict__ W,  // 64x64 layer
                                  const float* __restrict__ b,
                                  short* __restrict__ Wt,
                                  float* __restrict__ bs) {
  __shared__ float red[2][4][64];
  __shared__ float sa[64];
  int t = threadIdx.x;
  int o = t & 63, part = t >> 6;  // 4 parts x 32 shards
  {
    float s = 0.f, q = 0.f;
    for (int i = part * 32; i < part * 32 + 32; ++i) {
      s += shards[i * 128 + o];
      q += shards[i * 128 + 64 + o];
    }
    red[0][part][o] = s;
    red[1][part][o] = q;
  }
  __syncthreads();
  if (t < 64) {
    float st = red[0][0][t] + red[0][1][t] + red[0][2][t] + red[0][3][t];
    float qt = red[1][0][t] + red[1][1][t] + red[1][2][t] + red[1][3][t];
    float mu = st / cnt;
    float var = fmaxf(qt / cnt - mu * mu, 0.f);
    float r = rsqrtf(var + BN_EPS);
    float a = gamma[t] * r;
    float c = beta[t] - mu * a;
    sa[t] = a;
    if (blockIdx.x == 0) bs[t] = a * b[t] + c;
  }
  __syncthreads();
  int i = blockIdx.x * 256 + t;
  if (i < 64 * 64) {
    int k = i % 64, n = i / 64;
    Wt[i] = f2bs(W[k * 64 + n] * sa[n]);
  }
}

// ---- 32x32x16 MFMA edge helpers --------------------------------------------

__device__ __forceinline__ void stage_w1(const short* __restrict__ Wt,
                                         short* Lw, int t) {
#pragma unroll
  for (int i = 0; i < 5; ++i) {
    int c = t + i * 256;
    int col = c / 20, ch = c % 20;
    *(short8*)&Lw[col * LW1S + ch * 8] = *(const short8*)&Wt[col * 160 + ch * 8];
  }
}
__device__ __forceinline__ void stage_w2(const short* __restrict__ Wt,
                                         short* Lw, int t) {
#pragma unroll
  for (int i = 0; i < 2; ++i) {
    int c = t + i * 256;
    int col = c >> 3, ch = c & 7;
    *(short8*)&Lw[col * LW2S + ch * 8] = *(const short8*)&Wt[col * 64 + ch * 8];
  }
}

// standard GEMM1 (pass_a): A=features (i=edge), B=W1, bias uniform per lane
__device__ __forceinline__ void gemm1_32(const short* __restrict__ hbf,
                                         const short* Lw1,
                                         const float* __restrict__ bias, int d,
                                         int sx, short eav, int me, int hl,
                                         floatx16 acc[2]) {
  const short* hd = hbf + (size_t)d * 64 + hl * 8;
  const short* hs = hbf + (size_t)sx * 64 + hl * 8;
  short8 A[8];
#pragma unroll
  for (int kc = 0; kc < 4; ++kc) A[kc] = *(const short8*)(hd + kc * 16);
#pragma unroll
  for (int kc = 0; kc < 4; ++kc) A[4 + kc] = *(const short8*)(hs + kc * 16);
  short8 a8 = {0, 0, 0, 0, 0, 0, 0, 0};
  if (hl == 0) a8[0] = eav;
#pragma unroll
  for (int nt = 0; nt < 2; ++nt) {
    int col = nt * 32 + me;
    float bv = bias[col];
    floatx16 a;
#pragma unroll
    for (int r = 0; r < 16; ++r) a[r] = bv;
    const short* wp = Lw1 + col * LW1S + hl * 8;
#pragma unroll
    for (int kc = 0; kc < 8; ++kc) {
      short8 B = *(const short8*)(wp + kc * 16);
      a = MFMA32(A[kc], B, a, 0, 0, 0);
    }
    short8 B8 = *(const short8*)(wp + 128);
    a = MFMA32(a8, B8, a, 0, 0, 0);
    acc[nt] = a;
  }
}

// gather the 8 feature fragments (dst row + src row) for one edge column
__device__ __forceinline__ void load_frag(const short* __restrict__ hbf, int d,
                                          int sx, int hl, short8 Bf[8]) {
  int dc = d < 0 ? 0 : d;
  const short* hd = hbf + (size_t)dc * 64 + hl * 8;
  const short* hs = hbf + (size_t)sx * 64 + hl * 8;
#pragma unroll
  for (int kc = 0; kc < 4; ++kc) Bf[kc] = *(const short8*)(hd + kc * 16);
#pragma unroll
  for (int kc = 0; kc < 4; ++kc) Bf[4 + kc] = *(const short8*)(hs + kc * 16);
}

// swapped GEMM1 MFMA chain from pre-loaded fragments: A=W1 (i=n1),
// B=features (j=edge) -> D'[n1][edge]
__device__ __forceinline__ void gemm1T_mfma(const short* Lw1,
                                            const short8 Bf[8], short eav,
                                            int me, int hl, floatx16 acc[2]) {
  short8 b8 = {0, 0, 0, 0, 0, 0, 0, 0};
  if (hl == 0) b8[0] = eav;
#pragma unroll
  for (int nt = 0; nt < 2; ++nt) {
    floatx16 a;
#pragma unroll
    for (int r = 0; r < 16; ++r) a[r] = 0.f;
    const short* wp = Lw1 + (nt * 32 + me) * LW1S + hl * 8;
#pragma unroll
    for (int kc = 0; kc < 8; ++kc) {
      short8 A = *(const short8*)(wp + kc * 16);
      a = MFMA32(A, Bf[kc], a, 0, 0, 0);
    }
    short8 A8 = *(const short8*)(wp + 128);
    a = MFMA32(A8, b8, a, 0, 0, 0);
    acc[nt] = a;
  }
}

// swapped GEMM1 (pass b): loads + MFMA in one go
__device__ __forceinline__ void gemm1T_32(const short* __restrict__ hbf,
                                          const short* Lw1, int d, int sx,
                                          short eav, int me, int hl,
                                          floatx16 acc[2]) {
  short8 Bf[8];
  load_frag(hbf, d, sx, hl, Bf);
  gemm1T_mfma(Lw1, Bf, eav, me, hl, acc);
}

// z^T (col=edge, row=n1) + bias + relu -> Lz[edge][n1]; 8x b64 packed writes
__device__ __forceinline__ void write_z(short* Lz, const floatx16 acc[2],
                                        const float b1v[2][16], int w, int me,
                                        int hl) {
#pragma unroll
  for (int nt = 0; nt < 2; ++nt)
#pragma unroll
    for (int g4 = 0; g4 < 4; ++g4) {
      int n1b = nt * 32 + 8 * g4 + 4 * hl;
      short4v pk;
#pragma unroll
      for (int j = 0; j < 4; ++j) {
        int r = g4 * 4 + j;
        pk[j] = f2bs_fast(fmaxf(acc[nt][r] + b1v[nt][r], 0.f));
      }
      *(short4v*)&Lz[(w * 32 + me) * LYS + n1b] = pk;
    }
}

// standard GEMM2: A=z (i=edge) from Lz, B=W2 (j=n2), bias uniform per lane
__device__ __forceinline__ void gemm2_32(const short* Lz, const short* Lw2,
                                         const float* __restrict__ bias, int w,
                                         int me, int hl, floatx16 acc[2]) {
  short8 Z[4];
  const short* zp = &Lz[(w * 32 + me) * LYS + hl * 8];
#pragma unroll
  for (int kc = 0; kc < 4; ++kc) Z[kc] = *(const short8*)(zp + kc * 16);
#pragma unroll
  for (int nt = 0; nt < 2; ++nt) {
    int col = nt * 32 + me;
    float bv = bias[col];
    floatx16 a;
#pragma unroll
    for (int r = 0; r < 16; ++r) a[r] = bv;
    const short* wp = Lw2 + col * LW2S + hl * 8;
#pragma unroll
    for (int kc = 0; kc < 4; ++kc) {
      short8 B = *(const short8*)(wp + kc * 16);
      a = MFMA32(Z[kc], B, a, 0, 0, 0);
    }
    acc[nt] = a;
  }
}

__device__ __forceinline__ void stats32_acc(const floatx16 acc[2], int idx0,
                                            int w, int hl, int E, bool full,
                                            float sa[2], float qa[2]) {
#pragma unroll
  for (int nt = 0; nt < 2; ++nt) {
    float s = 0.f, q = 0.f;
#pragma unroll
    for (int r = 0; r < 16; ++r) {
      float v = acc[nt][r];
      if (!full) {
        int row = (r & 3) + 8 * (r >> 2) + 4 * hl;
        if (idx0 + w * 32 + row >= E) v = 0.f;
      }
      s += v;
      q += v * v;
    }
    s += __shfl_down(s, 32, 64);
    q += __shfl_down(q, 32, 64);
    sa[nt] += s;
    qa[nt] += q;
  }
}

__device__ __forceinline__ void stats_epilogue(float sred[4][128],
                                               const float sa[2],
                                               const float qa[2], int w,
                                               int lane, int t,
                                               float* __restrict__ stat,
                                               int shard) {
  if (lane < 32) {
#pragma unroll
    for (int nt = 0; nt < 2; ++nt) {
      sred[w][nt * 32 + lane] = sa[nt];
      sred[w][64 + nt * 32 + lane] = qa[nt];
    }
  }
  __syncthreads();
  if (t < 128) {
    float v = sred[0][t] + sred[1][t] + sred[2][t] + sred[3][t];
    atomicAdd(&stat[(size_t)shard * 128 + t], v);
  }
}

// ---- edge pass kernels -----------------------------------------------------

__global__ __launch_bounds__(256) void edge_pass_a(
    const short* __restrict__ hbf, const short* __restrict__ Wt1,
    const float* __restrict__ b1, const int* __restrict__ dd,
    const int* __restrict__ dsr, const short* __restrict__ es,
    float* __restrict__ stat, int E, int Epad) {
  __shared__ __align__(16) short Lw1[64 * LW1S];
  __shared__ float sred[4][128];
  int t = threadIdx.x;
  stage_w1(Wt1, Lw1, t);
  __syncthreads();
  int w = t >> 6, lane = t & 63, me = lane & 31, hl = lane >> 5;
  float sa[2] = {0.f, 0.f}, qa[2] = {0.f, 0.f};
  for (int it = 0; it < TPB; ++it) {
    int idx0 = (blockIdx.x * TPB + it) * 128;
    if (idx0 >= Epad) break;
    int eg = idx0 + w * 32 + me;
    int d = dd[eg];
    int dc = d < 0 ? 0 : d;
    int sx = dsr[eg];
    short eav = es[eg];
    floatx16 acc[2];
    gemm1_32(hbf, Lw1, b1, dc, sx, eav, me, hl, acc);
    stats32_acc(acc, idx0, w, hl, E, idx0 + 128 <= E, sa, qa);
  }
  stats_epilogue(sred, sa, qa, w, lane, t, stat, blockIdx.x & (NSH - 1));
}

__global__ __launch_bounds__(256) void edge_pass_b(
    const short* __restrict__ hbf, const short* __restrict__ Wt1s,
    const float* __restrict__ b1s, const int* __restrict__ dd,
    const int* __restrict__ dsr, const short* __restrict__ es,
    const short* __restrict__ Wt2, const float* __restrict__ b2,
    float* __restrict__ stat, int E, int Epad) {
  __shared__ __align__(16) short Lw1[64 * LW1S];
  __shared__ __align__(16) short Lw2[64 * LW2S];
  __shared__ __align__(16) short Lz[128 * LYS];
  __shared__ float sred[4][128];
  int t = threadIdx.x;
  stage_w1(Wt1s, Lw1, t);
  stage_w2(Wt2, Lw2, t);
  __syncthreads();
  int w = t >> 6, lane = t & 63, me = lane & 31, hl = lane >> 5;
  float b1v[2][16];
#pragma unroll
  for (int nt = 0; nt < 2; ++nt)
#pragma unroll
    for (int r = 0; r < 16; ++r)
      b1v[nt][r] = b1s[nt * 32 + (r & 3) + 8 * (r >> 2) + 4 * hl];
  float sa[2] = {0.f, 0.f}, qa[2] = {0.f, 0.f};
  for (int it = 0; it < TPB; ++it) {
    int idx0 = (blockIdx.x * TPB + it) * 128;
    if (idx0 >= Epad) break;
    int eg = idx0 + w * 32 + me;
    int d = dd[eg];
    int dc = d < 0 ? 0 : d;
    int sx = dsr[eg];
    short eav = es[eg];
    floatx16 acc[2];
    gemm1T_32(hbf, Lw1, dc, sx, eav, me, hl, acc);
    write_z(Lz, acc, b1v, w, me, hl);  // wave-private rows: no barrier
    floatx16 acc2[2];
    gemm2_32(Lz, Lw2, b2, w, me, hl, acc2);  // raw y2 for stats
    stats32_acc(acc2, idx0, w, hl, E, idx0 + 128 <= E, sa, qa);
  }
  stats_epilogue(sred, sa, qa, w, lane, t, stat, blockIdx.x & (NSH - 1));
}

// pipelined pass_c: gathers 1 tile ahead (issued BEFORE current tile's
// atomics -> in-order vmcnt never stalls gathers on atomic retirement),
// indices 2 ahead, wave-private dst staging, zero per-tile barriers.
__global__ __launch_bounds__(256) void edge_pass_c(
    const short* __restrict__ hbf, const short* __restrict__ Wt1s,
    const float* __restrict__ b1s, const int* __restrict__ dd,
    const int* __restrict__ dsr, const short* __restrict__ es,
    const short* __restrict__ Wt2s, const float* __restrict__ b2s,
    float* __restrict__ aggr, int E, int Epad) {
  __shared__ __align__(16) short Lw1[64 * LW1S];
  __shared__ __align__(16) short Lw2[64 * LW2S];
  __shared__ __align__(16) short Lz[128 * LYS];
  __shared__ int sdstw[4][32];  // wave-private dst windows
  int t = threadIdx.x;
  stage_w1(Wt1s, Lw1, t);
  stage_w2(Wt2s, Lw2, t);
  int w = t >> 6, lane = t & 63, me = lane & 31, hl = lane >> 5;
  const int base0 = blockIdx.x * TPB * 128;
  // index pipeline (2 ahead): cur / next
  int d_c, sx_c, d_n, sx_n;
  short eav_c, eav_n;
  {
    int eg = base0 + w * 32 + me;  // tile 0 (always valid: base0 < Epad)
    d_c = dd[eg];
    sx_c = dsr[eg];
    eav_c = es[eg];
    int i1 = base0 + 128;
    if (i1 < Epad) {
      d_n = dd[i1 + w * 32 + me];
      sx_n = dsr[i1 + w * 32 + me];
      eav_n = es[i1 + w * 32 + me];
    } else {
      d_n = -1;
      sx_n = 0;
      eav_n = 0;
    }
  }
  // fragment pipeline (1 ahead): prefetch tile 0
  short8 Bf_c[8], Bf_n[8];
  load_frag(hbf, d_c, sx_c, hl, Bf_c);
  __syncthreads();  // Lw1/Lw2 staged (single barrier in the whole kernel)
  float b1v[2][16];
#pragma unroll
  for (int nt = 0; nt < 2; ++nt)
#pragma unroll
    for (int r = 0; r < 16; ++r)
      b1v[nt][r] = b1s[nt * 32 + (r & 3) + 8 * (r >> 2) + 4 * hl];
#pragma unroll
  for (int it = 0; it < TPB; ++it) {
    int idx0 = base0 + it * 128;
    if (idx0 < Epad) {
      bool nv = (idx0 + 128) < Epad;  // tile it+1 exists (uniform)
      // 1. issue NEXT tile's gathers first (ahead of this tile's atomics)
      if (nv) load_frag(hbf, d_n, sx_n, hl, Bf_n);
      // 2. issue tile it+2's index loads
      int d_2 = -1, sx_2 = 0;
      short eav_2 = 0;
      int i2 = idx0 + 256;
      if (it + 2 < TPB && i2 < Epad) {
        d_2 = dd[i2 + w * 32 + me];
        sx_2 = dsr[i2 + w * 32 + me];
        eav_2 = es[i2 + w * 32 + me];
      }
      // 3. stage own dst window (wave-private; lgkmcnt-ordered, no barrier)
      if (lane < 32) sdstw[w][lane] = d_c;
      // 4. compute current tile
      floatx16 acc[2];
      gemm1T_mfma(Lw1, Bf_c, eav_c, me, hl, acc);
      write_z(Lz, acc, b1v, w, me, hl);  // wave-private rows
      floatx16 acc2[2];
      gemm2_32(Lz, Lw2, b2s, w, me, hl, acc2);  // BN2-folded y2
      // 5. register segsum: lane holds cols (me, me+32) over its 16 sorted
      // edges; half-lane partial flushes OK (atomics commute, runs
      // contiguous); padded edges (dst=-1) never flush. Atomics are
      // fire-and-forget: nothing issued after them is waited on this tile.
      float s0 = 0.f, s1 = 0.f;
      int d2 = sdstw[w][4 * hl];
#pragma unroll
      for (int g4 = 0; g4 < 4; ++g4) {
#pragma unroll
        for (int j = 0; j < 4; ++j) {
          int r = g4 * 4 + j;
          s0 += fmaxf(acc2[0][r], 0.f);
          s1 += fmaxf(acc2[1][r], 0.f);
          int offn;
          if (j == 3)
            offn = (g4 == 3) ? -1 : 8 * (g4 + 1) + 4 * hl;
          else
            offn = 8 * g4 + 4 * hl + j + 1;
          int dn = (offn < 0) ? -2 : sdstw[w][offn];
          if (d2 != dn) {
            if (d2 >= 0) {
              atomicAdd(&aggr[(size_t)d2 * 64 + me], s0);
              atomicAdd(&aggr[(size_t)d2 * 64 + me + 32], s1);
            }
            s0 = 0.f;
            s1 = 0.f;
          }
          d2 = dn;
        }
      }
      // 6. rotate pipeline state
#pragma unroll
      for (int kc = 0; kc < 8; ++kc) Bf_c[kc] = Bf_n[kc];
      d_c = d_n;
      sx_c = sx_n;
      eav_c = eav_n;
      d_n = d_2;
      sx_n = sx_2;
      eav_n = eav_2;
    }
  }
}

// ---- node pipeline (r5 fp32 tiled; node_gemm1 zeroes aggr after read) ------

__device__ __forceinline__ void gemm_r2c8(const float* __restrict__ As,
                                          const float* __restrict__ W, int K,
                                          int rg, int cg, float acc[2][8]) {
  const float* ap = As + rg * 2;
  const float* wp = W + cg * 8;
#pragma unroll 4
  for (int k = 0; k < K; ++k) {
    float2 a = *(const float2*)&ap[k * ASW];
    float4 w0 = *(const float4*)&wp[k * 64];
    float4 w1 = *(const float4*)&wp[k * 64 + 4];
    float wv[8] = {w0.x, w0.y, w0.z, w0.w, w1.x, w1.y, w1.z, w1.w};
#pragma unroll
    for (int j = 0; j < 8; ++j) {
      acc[0][j] += a.x * wv[j];
      acc[1][j] += a.y * wv[j];
    }
  }
}

__device__ __forceinline__ void stats_r2c8(const float acc[2][8],
                                           float* __restrict__ shard, int t,
                                           int cg) {
  float s[8], q[8];
#pragma unroll
  for (int j = 0; j < 8; ++j) {
    s[j] = acc[0][j] + acc[1][j];
    q[j] = acc[0][j] * acc[0][j] + acc[1][j] * acc[1][j];
  }
#pragma unroll
  for (int off = 32; off >= 8; off >>= 1) {
#pragma unroll
    for (int j = 0; j < 8; ++j) {
      s[j] += __shfl_down(s[j], off, 64);
      q[j] += __shfl_down(q[j], off, 64);
    }
  }
  if (((t & 63) >> 3) == 0) {
#pragma unroll
    for (int j = 0; j < 8; ++j) {
      atomicAdd(&shard[cg * 8 + j], s[j]);
      atomicAdd(&shard[64 + cg * 8 + j], q[j]);
    }
  }
}

__global__ __launch_bounds__(256) void node_gemm1_v3(
    const float* __restrict__ h, float* __restrict__ aggr,
    const float* __restrict__ W, const float* __restrict__ b,
    float* __restrict__ u1, float* __restrict__ stat, int N) {
  __shared__ __align__(16) float As[128 * ASW];
  int n0 = blockIdx.x * 64;
  int t = threadIdx.x;
  int c = t & 63, g = t >> 6;
  for (int n = g; n < 64; n += 4) {
    int idx = n0 + n;
    bool v = idx < N;
    As[c * ASW + n] = v ? h[(size_t)idx * 64 + c] : 0.f;
    if (v) {
      As[(64 + c) * ASW + n] = aggr[(size_t)idx * 64 + c];
      aggr[(size_t)idx * 64 + c] = 0.f;  // self-clean for next layer's pass_c
    } else {
      As[(64 + c) * ASW + n] = 0.f;
    }
  }
  __syncthreads();
  int rg = t >> 3, cg = t & 7;
  float acc[2][8];
#pragma unroll
  for (int i = 0; i < 2; ++i)
#pragma unroll
    for (int j = 0; j < 8; ++j) acc[i][j] = b[cg * 8 + j];
  gemm_r2c8(As, W, 128, rg, cg, acc);
#pragma unroll
  for (int i = 0; i < 2; ++i) {
    int idx = n0 + rg * 2 + i;
    if (idx < N) {
      *(float4*)&u1[(size_t)idx * 64 + cg * 8] =
          make_float4(acc[i][0], acc[i][1], acc[i][2], acc[i][3]);
      *(float4*)&u1[(size_t)idx * 64 + cg * 8 + 4] =
          make_float4(acc[i][4], acc[i][5], acc[i][6], acc[i][7]);
    } else {
#pragma unroll
      for (int j = 0; j < 8; ++j) acc[i][j] = 0.f;
    }
  }
  stats_r2c8(acc, stat + (size_t)(blockIdx.x & (NSH - 1)) * 128, t, cg);
}

__global__ __launch_bounds__(256) void node_gemm2_v3(
    const float* __restrict__ u1, const float* __restrict__ ac,
    const float* __restrict__ W, const float* __restrict__ b,
    float* __restrict__ u2, float* __restrict__ stat, int N) {
  __shared__ __align__(16) float As[64 * ASW];
  int n0 = blockIdx.x * 64;
  int t = threadIdx.x;
  int c = t & 63, g = t >> 6;
  float a1 = ac[c], c1 = ac[64 + c];
  for (int n = g; n < 64; n += 4) {
    int idx = n0 + n;
    bool v = idx < N;
    As[c * ASW + n] = v ? fmaxf(u1[(size_t)idx * 64 + c] * a1 + c1, 0.f) : 0.f;
  }
  __syncthreads();
  int rg = t >> 3, cg = t & 7;
  float acc[2][8];
#pragma unroll
  for (int i = 0; i < 2; ++i)
#pragma unroll
    for (int j = 0; j < 8; ++j) acc[i][j] = b[cg * 8 + j];
  gemm_r2c8(As, W, 64, rg, cg, acc);
#pragma unroll
  for (int i = 0; i < 2; ++i) {
    int idx = n0 + rg * 2 + i;
    if (idx < N) {
      *(float4*)&u2[(size_t)idx * 64 + cg * 8] =
          make_float4(acc[i][0], acc[i][1], acc[i][2], acc[i][3]);
      *(float4*)&u2[(size_t)idx * 64 + cg * 8 + 4] =
          make_float4(acc[i][4], acc[i][5], acc[i][6], acc[i][7]);
    } else {
#pragma unroll
      for (int j = 0; j < 8; ++j) acc[i][j] = 0.f;
    }
  }
  stats_r2c8(acc, stat + (size_t)(blockIdx.x & (NSH - 1)) * 128, t, cg);
}

__global__ void residual_kernel(float* __restrict__ h, short* __restrict__ hb,
                                const float* __restrict__ u2,
                                const float* __restrict__ ac, int total) {
  int gid = blockIdx.x * blockDim.x + threadIdx.x;
  if (gid >= total) return;
  int o = gid & 63;
  float v = u2[gid] * ac[o] + ac[64 + o];
  float nv = h[gid] + fmaxf(v, 0.f);
  h[gid] = nv;
  hb[gid] = f2bs(nv);
}

__global__ void pred_kernel(const float* __restrict__ h,
                            const float* __restrict__ W,
                            const float* __restrict__ b,
                            float* __restrict__ out, int N) {
  int n = blockIdx.x * blockDim.x + threadIdx.x;
  if (n >= N) return;
  float acc = b[0];
  const float* hr = h + (size_t)n * 64;
#pragma unroll
  for (int o = 0; o < 64; ++o) acc += hr[o] * W[o];
  out[n] = acc;
}

// ---- launch ----------------------------------------------------------------

extern "C" void kernel_launch(void* const* d_in, const int* in_sizes, int n_in,
                              void* d_out, int out_size, void* d_ws,
                              size_t ws_size, hipStream_t stream) {
  const float* x = (const float*)d_in[0];
  const int* ei = (const int*)d_in[1];
  const float* ea = (const float*)d_in[2];
  const float* lin_W = (const float*)d_in[3];
  const float* lin_b = (const float*)d_in[4];
  const float* msg_W1 = (const float*)d_in[5];
  const float* msg_b1 = (const float*)d_in[6];
  const float* msg_g1 = (const float*)d_in[7];
  const float* msg_be1 = (const float*)d_in[8];
  const float* msg_W2 = (const float*)d_in[9];
  const float* msg_b2 = (const float*)d_in[10];
  const float* msg_g2 = (const float*)d_in[11];
  const float* msg_be2 = (const float*)d_in[12];
  const float* upd_W1 = (const float*)d_in[13];
  const float* upd_b1 = (const float*)d_in[14];
  const float* upd_g1 = (const float*)d_in[15];
  const float* upd_be1 = (const float*)d_in[16];
  const float* upd_W2 = (const float*)d_in[17];
  const float* upd_b2 = (const float*)d_in[18];
  const float* upd_g2 = (const float*)d_in[19];
  const float* upd_be2 = (const float*)d_in[20];
  const float* pred_W = (const float*)d_in[21];
  const float* pred_b = (const float*)d_in[22];
  float* out = (float*)d_out;

  const int N = in_sizes[0] / 6;
  const int E = in_sizes[1] / 2;
  const int L = 4;
  const int Epad = ((E + 127) / 128) * 128;

  char* p = (char*)d_ws;
  auto alloc = [&](size_t bytes) {
    void* r = (void*)p;
    p += (bytes + 255) & ~(size_t)255;
    return r;
  };
  float* h = (float*)alloc((size_t)N * 64 * 4);
  short* hb = (short*)alloc((size_t)N * 64 * 2);
  float* aggr = (float*)alloc((size_t)N * 64 * 4);          // contiguous with
  float* stats = (float*)alloc((size_t)4 * NSH * 128 * 4);  // stats
  float* acu1 = (float*)alloc(128 * 4);
  float* acu2 = (float*)alloc(128 * 4);
  float* b1s = (float*)alloc(64 * 4);
  float* b2s = (float*)alloc(64 * 4);
  float* u1 = (float*)alloc((size_t)N * 64 * 4);
  float* u2 = (float*)alloc((size_t)N * 64 * 4);
  int* deg = (int*)alloc((size_t)N * 4);
  int* offs = (int*)alloc((size_t)N * 4);
  int* cnt = (int*)alloc((size_t)N * 4);
  int* sorted = (int*)alloc((size_t)E * 4);
  int* dd = (int*)alloc((size_t)Epad * 4);
  int* dsr = (int*)alloc((size_t)Epad * 4);
  short* es = (short*)alloc((size_t)Epad * 2);
  short* Wt1 = (short*)alloc((size_t)L * 64 * 160 * 2);
  short* Wt2 = (short*)alloc((size_t)L * 64 * 64 * 2);
  short* Wt1s = (short*)alloc((size_t)64 * 160 * 2);
  short* Wt2s = (short*)alloc((size_t)64 * 64 * 2);

  const int B = 256;
  const size_t REG = (size_t)NSH * 128;
  int gridE256 = (E + 255) / 256;
  int NT = Epad / 128;
  int gridEdge = (NT + TPB - 1) / TPB;
  int gridM64 = (N + 63) / 64;
  int gridN64 = (N * 64 + B - 1) / B;
  int gridN = (N + B - 1) / B;

  // setup
  hipMemsetAsync(deg, 0, (size_t)N * 4, stream);
  hipMemsetAsync(cnt, 0, (size_t)N * 4, stream);
  hipMemsetAsync(aggr, 0, (size_t)N * 64 * 4, stream);  // once; then
                                                        // node_gemm1 cleans
  lin_in_kernel<<<gridN64, B, 0, stream>>>(x, lin_W, lin_b, h, hb, N);
  deg_kernel<<<gridE256, B, 0, stream>>>(ei, deg, E);
  scan_kernel<<<1, 1024, 0, stream>>>(deg, offs, N);
  fill_kernel<<<gridE256, B, 0, stream>>>(ei, offs, cnt, sorted, E);
  gather_edges_kernel<<<(Epad + 255) / 256, B, 0, stream>>>(ei, sorted, ea, dd,
                                                            dsr, es, E, Epad);
  pack_w1_kernel<<<(L * 64 * 160 + 255) / 256, B, 0, stream>>>(msg_W1, Wt1, L);
  pack_w2_kernel<<<(L * 64 * 64 + 255) / 256, B, 0, stream>>>(msg_W2, Wt2, L);

  for (int l = 0; l < L; ++l) {
    const short* Wt1l = Wt1 + (size_t)l * 64 * 160;
    const short* Wt2l = Wt2 + (size_t)l * 64 * 64;
    const float* U1 = upd_W1 + (size_t)l * 128 * 64;
    const float* U2 = upd_W2 + (size_t)l * 64 * 64;
    hipMemsetAsync(stats, 0, (size_t)4 * REG * 4, stream);  // stats only
    edge_pass_a<<<gridEdge, 256, 0, stream>>>(hb, Wt1l, msg_b1 + l * 64, dd,
                                              dsr, es, stats, E, Epad);
    bn_finalize_pack1<<<(64 * 160 + 255) / 256, B, 0, stream>>>(
        stats, msg_g1 + l * 64, msg_be1 + l * 64, (float)E,
        msg_W1 + (size_t)l * 129 * 64, msg_b1 + l * 64, Wt1s, b1s);
    edge_pass_b<<<gridEdge, 256, 0, stream>>>(hb, Wt1s, b1s, dd, dsr, es, Wt2l,
                                              msg_b2 + l * 64, stats + REG, E,
                                              Epad);
    bn_finalize_pack2<<<(64 * 64 + 255) / 256, B, 0, stream>>>(
        stats + REG, msg_g2 + l * 64, msg_be2 + l * 64, (float)E,
        msg_W2 + (size_t)l * 64 * 64, msg_b2 + l * 64, Wt2s, b2s);
    edge_pass_c<<<gridEdge, 256, 0, stream>>>(hb, Wt1s, b1s, dd, dsr, es, Wt2s,
                                              b2s, aggr, E, Epad);
    node_gemm1_v3<<<gridM64, 256, 0, stream>>>(h, aggr, U1, upd_b1 + l * 64,
                                               u1, stats + 2 * REG, N);
    bn_finalize_kernel<<<1, 256, 0, stream>>>(stats + 2 * REG, upd_g1 + l * 64,
                                              upd_be1 + l * 64, (float)N,
                                              acu1);
    node_gemm2_v3<<<gridM64, 256, 0, stream>>>(u1, acu1, U2, upd_b2 + l * 64,
                                               u2, stats + 3 * REG, N);
    bn_finalize_kernel<<<1, 256, 0, stream>>>(stats + 3 * REG, upd_g2 + l * 64,
                                              upd_be2 + l * 64, (float)N,
                                              acu2);
    residual_kernel<<<gridN64, B, 0, stream>>>(h, hb, u2, acu2, N * 64);
  }
  pred_kernel<<<gridN, B, 0, stream>>>(h, pred_W, pred_b, out, N);
}